// Round 14
// baseline (337.210 us; speedup 1.0000x reference)
//
#include <hip/hip_runtime.h>
#include <hip/hip_bf16.h>

// GAT forward, MI355X. N=4096, NFEAT=1024, NHID=128, NHEADS=8, NCLASS=64.
// Inputs/outputs fp32 -> bf16 internally.
// Round 14: r13 + (a) f1/f2 zeroing folded into prep (memset dispatch gone),
// (b) combine1 fused into gemm2c B-staging (hcat never materialized when
// js1>1; bit-identical values). Launches 8 -> 6. attn kernels r13-verbatim.

#define NN    4096
#define NF    1024
#define DH    128
#define NHEADS 8
#define NCLS  64
#define ALPHA 0.2f
#define LOG2E 1.44269504f

using short8 = __attribute__((ext_vector_type(8))) short;
using f32x4  = __attribute__((ext_vector_type(4))) float;
using int4v  = __attribute__((ext_vector_type(4))) int;

static __device__ __forceinline__ float bf2f(unsigned short h) {
    return __uint_as_float(((unsigned int)h) << 16);
}
static __device__ __forceinline__ unsigned short f2bf(float f) {
    unsigned int u = __float_as_uint(f);
    u = (u + 0x7fffu + ((u >> 16) & 1u)) >> 16;
    return (unsigned short)u;
}
static __device__ __forceinline__ float fast_exp2(float x) {
    return __builtin_amdgcn_exp2f(x);
}

__global__ __launch_bounds__(256) void diag_fill(
    float* __restrict__ out, int n, float val)
{
    int i = blockIdx.x * 256 + threadIdx.x;
    if (i < n) out[i] = val;
}

// ---------------------------------------------------------------- prep (fused)
// [0,16384): bitmask; [16384,20480): x convert; [20480,21632): W/Wo transpose;
// 21632: a1/a2; 21633: ao1/ao2; [21634,21698): zero f1/f2 (256KB)
__global__ __launch_bounds__(256) void prep(
    const float* __restrict__ x, const int* __restrict__ adj,
    const float* __restrict__ W, const float* __restrict__ Wo,
    const float* __restrict__ a1, const float* __restrict__ a2,
    const float* __restrict__ ao1, const float* __restrict__ ao2,
    unsigned short* __restrict__ xB, unsigned int* __restrict__ bm,
    unsigned short* __restrict__ WT, unsigned short* __restrict__ WoT,
    unsigned short* __restrict__ a1B, unsigned short* __restrict__ a2B,
    unsigned short* __restrict__ ao1B, unsigned short* __restrict__ ao2B,
    float* __restrict__ f1z)
{
    __shared__ unsigned short tile[32][33];
    int b = blockIdx.x, t = threadIdx.x;
    if (b < 16384) {                       // bitmask (int4 + shfl-OR)
        long t4 = (long)b * 256 + t;
        int4v v = ((const int4v*)adj)[t4];
        unsigned nib = (v[0] > 0 ? 1u : 0u) | (v[1] > 0 ? 2u : 0u)
                     | (v[2] > 0 ? 4u : 0u) | (v[3] > 0 ? 8u : 0u);
        int l = t & 63;
        unsigned w = nib << (4 * (l & 7));
        w |= __shfl_xor(w, 1);
        w |= __shfl_xor(w, 2);
        w |= __shfl_xor(w, 4);
        if ((l & 7) == 0) bm[t4 >> 3] = w;
    } else if (b < 20480) {                // x fp32 -> bf16 (float4/thread)
        long i = ((long)(b - 16384) * 256 + t) * 4;
        float4 v = *(const float4*)&x[i];
        unsigned u0 = (unsigned)f2bf(v.x) | ((unsigned)f2bf(v.y) << 16);
        unsigned u1 = (unsigned)f2bf(v.z) | ((unsigned)f2bf(v.w) << 16);
        uint2 u; u.x = u0; u.y = u1;
        *(uint2*)&xB[i] = u;
    } else if (b < 21632) {                // transpose+convert W (z<8) / Wo (z=8)
        int tid = b - 20480;
        int z = tid >> 7;
        int rem = tid & 127;
        int bx = rem & 3, by = rem >> 2;
        const float* in; unsigned short* out; int C;
        if (z < 8) { in = W + (long)z * NF * DH; out = WT + (long)z * DH * NF; C = DH; }
        else       { in = Wo;                    out = WoT;                    C = NCLS; }
        int x0 = bx * 32, y0 = by * 32;
        if (x0 >= C) return;
        int tx = t & 31, ty = t >> 5;
        for (int yy = 0; yy < 32; yy += 8)
            tile[ty + yy][tx] = f2bf(in[(long)(y0 + ty + yy) * C + x0 + tx]);
        __syncthreads();
        for (int yy = 0; yy < 32; yy += 8)
            out[(long)(x0 + ty + yy) * NF + y0 + tx] = tile[tx][ty + yy];
    } else if (b == 21632) {
        for (int i = t; i < NHEADS * DH; i += 256) {
            a1B[i] = f2bf(a1[i]);
            a2B[i] = f2bf(a2[i]);
        }
    } else if (b == 21633) {
        if (t < NCLS) {
            ao1B[t] = f2bf(ao1[t]);
            ao2B[t] = f2bf(ao2[t]);
        }
    } else {                               // zero f1/f2: 64 blocks x 1024 floats
        long i = ((long)(b - 21634) * 256 + t) * 4;
        *(float4*)&f1z[i] = (float4){0.f, 0.f, 0.f, 0.f};
    }
}

// ---------------------------------------------------------------- gemm1 + fused f-scores (r11 verbatim)
__global__ __launch_bounds__(256) void gemm1_fs(
    const unsigned short* __restrict__ A, const unsigned short* __restrict__ Bt,
    unsigned short* __restrict__ Cc, const unsigned short* __restrict__ a1B,
    const unsigned short* __restrict__ a2B, float* __restrict__ f1,
    float* __restrict__ f2)
{
    __shared__ unsigned short Alds[64][72];
    __shared__ unsigned short Blds[128][72];
    __shared__ float s1l[128], s2l[128];
    int t = threadIdx.x;
    int w = t >> 6, l = t & 63;
    int h = blockIdx.z;
    long aoff = (long)h * DH * NF + (long)blockIdx.y * 64 * NF;
    long boff = (long)blockIdx.x * 128 * NF;
    if (t < 128) { s1l[t] = 0.f; s2l[t] = 0.f; }
    f32x4 acc[8];
#pragma unroll
    for (int i = 0; i < 8; ++i) acc[i] = (f32x4){0.f, 0.f, 0.f, 0.f};

    for (int k0 = 0; k0 < NF; k0 += 64) {
#pragma unroll
        for (int it = 0; it < 2; ++it) {
            int ci = it * 256 + t;
            int r = ci >> 3, c8 = (ci & 7) * 8;
            *(short8*)&Alds[r][c8] = *(const short8*)&A[aoff + (long)r * NF + k0 + c8];
        }
#pragma unroll
        for (int it = 0; it < 4; ++it) {
            int ci = it * 256 + t;
            int r = ci >> 3, c8 = (ci & 7) * 8;
            *(short8*)&Blds[r][c8] = *(const short8*)&Bt[boff + (long)r * NF + k0 + c8];
        }
        __syncthreads();
        int arow = w * 16 + (l & 15);
        int koff = (l >> 4) * 8;
#pragma unroll
        for (int kc = 0; kc < 2; ++kc) {
            short8 af = *(const short8*)&Alds[arow][kc * 32 + koff];
#pragma unroll
            for (int dt = 0; dt < 8; ++dt) {
                short8 bf = *(const short8*)&Blds[dt * 16 + (l & 15)][kc * 32 + koff];
                acc[dt] = __builtin_amdgcn_mfma_f32_16x16x32_bf16(af, bf, acc[dt], 0, 0, 0);
            }
        }
        __syncthreads();
    }
    long coff = (long)h * DH * NN + ((long)blockIdx.y * 64) * NN + blockIdx.x * 128;
    int mrow = w * 16 + (l >> 4) * 4;
    int dbase = blockIdx.y * 64;
#pragma unroll
    for (int dt = 0; dt < 8; ++dt) {
        int n = dt * 16 + (l & 15);
        float p1 = 0.f, p2 = 0.f;
#pragma unroll
        for (int r = 0; r < 4; ++r) {
            unsigned short bw = f2bf(acc[dt][r]);
            Cc[coff + (long)(mrow + r) * NN + n] = bw;
            float vf = bf2f(bw);
            int d = dbase + mrow + r;
            p1 += vf * bf2f(a1B[h * DH + d]);
            p2 += vf * bf2f(a2B[h * DH + d]);
        }
        atomicAdd(&s1l[n], p1);
        atomicAdd(&s2l[n], p2);
    }
    __syncthreads();
    if (t < 128) {
        int n = blockIdx.x * 128 + t;
        atomicAdd(&f1[h * NN + n], s1l[t] * LOG2E);
        atomicAdd(&f2[h * NN + n], s2l[t] * LOG2E);
    }
}

// ---------------------------------------------------------------- gemm2 + combinew + fused combine1
// B-staging reads attn1 partials (accp1,dsum1), normalizes+ELU inline
// (bit-identical to combine1) — hcat never materialized when js1>1.
__global__ __launch_bounds__(256) void gemm2c(
    const unsigned short* __restrict__ A, const unsigned short* __restrict__ accp1,
    const float* __restrict__ dsum1, const unsigned short* __restrict__ hcat,
    const unsigned short* __restrict__ ao1B, const unsigned short* __restrict__ ao2B,
    unsigned short* __restrict__ WhoT, float* __restrict__ g1, float* __restrict__ g2,
    int js1)
{
    __shared__ unsigned short Alds[64][72];
    __shared__ unsigned short Blds[64][72];
    __shared__ float s1l[64], s2l[64];
    __shared__ float sinv[64][NHEADS];
    int t = threadIdx.x;
    int w = t >> 6, l = t & 63;
    int n0 = blockIdx.x * 64;
    if (t < 64) { s1l[t] = 0.f; s2l[t] = 0.f; }
    if (js1 > 1) {
        for (int idx = t; idx < 64 * NHEADS; idx += 256) {
            int i = idx & 63, h = idx >> 6;
            float s = 0.f;
            for (int jz = 0; jz < js1; ++jz)
                s += dsum1[((long)jz * NHEADS + h) * NN + n0 + i];
            sinv[i][h] = 1.f / fmaxf(s, 1e-20f);
        }
    }
    __syncthreads();
    f32x4 acc[4];
#pragma unroll
    for (int i = 0; i < 4; ++i) acc[i] = (f32x4){0.f, 0.f, 0.f, 0.f};

    for (int k0 = 0; k0 < NF; k0 += 64) {
#pragma unroll
        for (int it = 0; it < 2; ++it) {
            int ci = it * 256 + t;
            int r = ci >> 3, c8 = (ci & 7) * 8;
            *(short8*)&Alds[r][c8] = *(const short8*)&A[(long)r * NF + k0 + c8];
        }
        int hh = k0 >> 7;                  // head for this k-chunk (64 | 128)
#pragma unroll
        for (int it = 0; it < 2; ++it) {   // B tile: row = hcat row n0+r, cols k0+c8..+8
            int ci = it * 256 + t;
            int r = ci >> 3, c8 = (ci & 7) * 8;
            if (js1 > 1) {
                float v[8] = {0.f, 0.f, 0.f, 0.f, 0.f, 0.f, 0.f, 0.f};
                for (int jz = 0; jz < js1; ++jz) {
                    uint4 pv = *(const uint4*)&accp1[((long)jz * NN + n0 + r) * (NHEADS * DH) + k0 + c8];
                    unsigned pu[4] = {pv.x, pv.y, pv.z, pv.w};
#pragma unroll
                    for (int q = 0; q < 4; ++q) {
                        v[q * 2]     += bf2f((unsigned short)(pu[q] & 0xFFFFu));
                        v[q * 2 + 1] += bf2f((unsigned short)(pu[q] >> 16));
                    }
                }
                float inv = sinv[r][hh];
                short8 bvec;
#pragma unroll
                for (int q = 0; q < 8; ++q) {
                    float o = v[q] * inv;
                    o = o > 0.f ? o : __expf(o) - 1.f;
                    bvec[q] = (short)f2bf(o);
                }
                *(short8*)&Blds[r][c8] = bvec;
            } else {
                *(short8*)&Blds[r][c8] = *(const short8*)&hcat[(long)(n0 + r) * NF + k0 + c8];
            }
        }
        __syncthreads();
        int arow = w * 16 + (l & 15);
        int koff = (l >> 4) * 8;
#pragma unroll
        for (int kc = 0; kc < 2; ++kc) {
            short8 af = *(const short8*)&Alds[arow][kc * 32 + koff];
#pragma unroll
            for (int dt = 0; dt < 4; ++dt) {
                short8 bf = *(const short8*)&Blds[dt * 16 + (l & 15)][kc * 32 + koff];
                acc[dt] = __builtin_amdgcn_mfma_f32_16x16x32_bf16(af, bf, acc[dt], 0, 0, 0);
            }
        }
        __syncthreads();
    }
    int mrow = w * 16 + (l >> 4) * 4;
#pragma unroll
    for (int dt = 0; dt < 4; ++dt) {
        int nl = dt * 16 + (l & 15);
        float p1 = 0.f, p2 = 0.f;
#pragma unroll
        for (int r = 0; r < 4; ++r) {
            int c = mrow + r;
            unsigned short bw = f2bf(acc[dt][r]);
            WhoT[(long)c * NN + n0 + nl] = bw;
            float vf = bf2f(bw);
            p1 += vf * bf2f(ao1B[c]);
            p2 += vf * bf2f(ao2B[c]);
        }
        atomicAdd(&s1l[nl], p1);
        atomicAdd(&s2l[nl], p2);
    }
    __syncthreads();
    if (t < 64) {
        g1[n0 + t] = s1l[t] * LOG2E;
        g2[n0 + t] = s2l[t] * LOG2E;
    }
}

// ------------------------------------------ legacy P-tile builder (fallback; exp2 domain)
static __device__ __forceinline__ float build_p16(
    unsigned int bits, float fi, const float* f2s, int pc0,
    short8& p0, short8& p1)
{
    float lsum = 0.f;
#pragma unroll
    for (int cc = 0; cc < 16; ++cc) {
        float wgt = 0.f;
        if ((bits >> cc) & 1u) {
            float e = fi + f2s[pc0 + cc];
            e = e > 0.f ? e : ALPHA * e;
            e = fminf(e, 60.f);
            wgt = fast_exp2(e);
        }
        unsigned short bw = f2bf(wgt);
        lsum += bf2f(bw);
        if (cc < 8) p0[cc] = (short)bw;
        else        p1[cc - 8] = (short)bw;
    }
    return lsum;
}

// ------------------------------------------ register A-fragment builder v3
static __device__ __forceinline__ void build_pfrag3(
    unsigned long long wpair, float fi, const float* __restrict__ f2g,
    int kgrp, short8& a0, short8& a1)
{
    int4v av0, av1;
#pragma unroll
    for (int kc = 0; kc < 2; ++kc) {
        unsigned bits = (unsigned)(wpair >> (kc * 32 + kgrp * 8)) & 0xFFu;
        const float4* fp = (const float4*)(f2g + kc * 32 + kgrp * 8);
        float4 fv0 = fp[0], fv1 = fp[1];
        float ev[8] = {fv0.x, fv0.y, fv0.z, fv0.w, fv1.x, fv1.y, fv1.z, fv1.w};
#pragma unroll
        for (int jj = 0; jj < 8; jj += 2) {
            float e0 = fi + ev[jj], e1 = fi + ev[jj + 1];
            e0 = fmaxf(e0, ALPHA * e0);
            e1 = fmaxf(e1, ALPHA * e1);
            float w0 = fast_exp2(e0), w1 = fast_exp2(e1);
            w0 = ((bits >> jj) & 1u) ? w0 : 0.f;
            w1 = ((bits >> (jj + 1)) & 1u) ? w1 : 0.f;
            float2 fv; fv.x = w0; fv.y = w1;
            __hip_bfloat162 pk = __float22bfloat162_rn(fv);
            unsigned pu; __builtin_memcpy(&pu, &pk, 4);
            if (kc == 0) av0[jj >> 1] = (int)pu;
            else         av1[jj >> 1] = (int)pu;
        }
    }
    a0 = __builtin_bit_cast(short8, av0);
    a1 = __builtin_bit_cast(short8, av1);
}

// ---------------------------------------------------------------- attn1 direct (ws fallback)
__global__ __launch_bounds__(256) void attn1_direct(
    const float* __restrict__ f1, const float* __restrict__ f2,
    const unsigned int* __restrict__ bm, const unsigned short* __restrict__ WhT,
    unsigned short* __restrict__ hcat)
{
    __shared__ unsigned short Plds[64][72];
    __shared__ unsigned short Wlds[128][72];
    __shared__ float f1s[64], f2s[64], ssum[64][4], srow[64];
    int t = threadIdx.x;
    int h = blockIdx.y;
    int i0 = blockIdx.x * 64;
    int w = t >> 6, l = t & 63;
    if (t < 64) f1s[t] = f1[h * NN + i0 + t];
    f32x4 acc[8];
#pragma unroll
    for (int i = 0; i < 8; ++i) acc[i] = (f32x4){0.f, 0.f, 0.f, 0.f};
    float psum = 0.f;
    int pr = t >> 2, pc0 = (t & 3) * 16;
    const unsigned short* Wh_h = WhT + (long)h * DH * NN;

    for (int j0 = 0; j0 < NN; j0 += 64) {
        if (t < 64) f2s[t] = f2[h * NN + j0 + t];
        __syncthreads();
        {
            unsigned int word = bm[(long)(i0 + pr) * (NN / 32) + (j0 >> 5) + ((pc0 >> 5) & 1)];
            unsigned int bits = (word >> (pc0 & 16)) & 0xFFFFu;
            short8 p0, p1;
            psum += build_p16(bits, f1s[pr], f2s, pc0, p0, p1);
            *(short8*)&Plds[pr][pc0]     = p0;
            *(short8*)&Plds[pr][pc0 + 8] = p1;
        }
#pragma unroll
        for (int it = 0; it < 4; ++it) {
            int ci = it * 256 + t;
            int d = ci >> 3, c8 = (ci & 7) * 8;
            *(short8*)&Wlds[d][c8] = *(const short8*)&Wh_h[(long)d * NN + j0 + c8];
        }
        __syncthreads();
        int arow = w * 16 + (l & 15);
        int koff = (l >> 4) * 8;
#pragma unroll
        for (int kc = 0; kc < 2; ++kc) {
            short8 af = *(const short8*)&Plds[arow][kc * 32 + koff];
#pragma unroll
            for (int dt = 0; dt < 8; ++dt) {
                short8 bf = *(const short8*)&Wlds[dt * 16 + (l & 15)][kc * 32 + koff];
                acc[dt] = __builtin_amdgcn_mfma_f32_16x16x32_bf16(af, bf, acc[dt], 0, 0, 0);
            }
        }
        __syncthreads();
    }
    ssum[pr][t & 3] = psum;
    __syncthreads();
    if (t < 64) srow[t] = ssum[t][0] + ssum[t][1] + ssum[t][2] + ssum[t][3];
    __syncthreads();
    int mrow = w * 16 + (l >> 4) * 4;
#pragma unroll
    for (int dt = 0; dt < 8; ++dt) {
        int d = dt * 16 + (l & 15);
#pragma unroll
        for (int r = 0; r < 4; ++r) {
            float v = acc[dt][r] / fmaxf(srow[mrow + r], 1e-20f);
            v = v > 0.f ? v : __expf(v) - 1.f;
            hcat[(long)(i0 + mrow + r) * (NHEADS * DH) + h * DH + d] = f2bf(v);
        }
    }
}

// ---------------------------------------------------------------- attn1 j-split (r13 verbatim)
__global__ __launch_bounds__(256) void attn1_part(
    const float* __restrict__ f1, const float* __restrict__ f2,
    const unsigned int* __restrict__ bm, const unsigned short* __restrict__ WhT,
    unsigned short* __restrict__ accp1, float* __restrict__ dsum1, int jspan)
{
    __shared__ unsigned short Wlds[128][72];
    int t = threadIdx.x;
    int h = blockIdx.y;
    int i0 = blockIdx.x * 64;
    int jz = blockIdx.z;
    int w = t >> 6, l = t & 63;
    int m = l & 15, kgrp = l >> 4;
    int myrow = i0 + w * 16 + m;
    float fi = f1[h * NN + myrow];
    const unsigned int* bmrow = bm + (long)myrow * (NN / 32);
    const float* f2h = f2 + (long)h * NN;
    const unsigned short* Wh_h = WhT + (long)h * DH * NN;
    short8 ones;
#pragma unroll
    for (int i = 0; i < 8; ++i) ones[i] = (short)0x3F80;   // bf16 1.0
    f32x4 acc[8];
#pragma unroll
    for (int i = 0; i < 8; ++i) acc[i] = (f32x4){0.f, 0.f, 0.f, 0.f};
    f32x4 accd = (f32x4){0.f, 0.f, 0.f, 0.f};

    for (int j0 = jz * jspan; j0 < (jz + 1) * jspan; j0 += 64) {
        unsigned long long wpair;
        __builtin_memcpy(&wpair, &bmrow[j0 >> 5], 8);
#pragma unroll
        for (int it = 0; it < 4; ++it) {          // stage Wh tile [128 d][64 j]
            int ci = it * 256 + t;
            int d = ci >> 3, c8 = (ci & 7) * 8;
            *(short8*)&Wlds[d][c8] = *(const short8*)&Wh_h[(long)d * NN + j0 + c8];
        }
        short8 a0, a1;
        build_pfrag3(wpair, fi, f2h + j0, kgrp, a0, a1);
        __syncthreads();
        accd = __builtin_amdgcn_mfma_f32_16x16x32_bf16(a0, ones, accd, 0, 0, 0);
        accd = __builtin_amdgcn_mfma_f32_16x16x32_bf16(a1, ones, accd, 0, 0, 0);
#pragma unroll
        for (int dt = 0; dt < 8; ++dt) {
            short8 b0 = *(const short8*)&Wlds[dt * 16 + m][kgrp * 8];
            acc[dt] = __builtin_amdgcn_mfma_f32_16x16x32_bf16(a0, b0, acc[dt], 0, 0, 0);
        }
#pragma unroll
        for (int dt = 0; dt < 8; ++dt) {
            short8 b1 = *(const short8*)&Wlds[dt * 16 + m][32 + kgrp * 8];
            acc[dt] = __builtin_amdgcn_mfma_f32_16x16x32_bf16(a1, b1, acc[dt], 0, 0, 0);
        }
        __syncthreads();
    }
    if (m == 0) {
#pragma unroll
        for (int r = 0; r < 4; ++r)
            dsum1[((long)jz * NHEADS + h) * NN + i0 + w * 16 + kgrp * 4 + r] = accd[r];
    }
    int mrow = w * 16 + kgrp * 4;
#pragma unroll
    for (int dt = 0; dt < 8; ++dt) {
        int d = dt * 16 + m;
#pragma unroll
        for (int r = 0; r < 4; ++r)
            accp1[((long)jz * NN + i0 + mrow + r) * (NHEADS * DH) + h * DH + d] = f2bf(acc[dt][r]);
    }
}

// ---------------------------------------------------------------- attn2 (r13 verbatim)
__global__ __launch_bounds__(256) void attn2(
    const float* __restrict__ g1, const float* __restrict__ g2,
    const unsigned int* __restrict__ bm, const unsigned short* __restrict__ WhoT,
    unsigned short* __restrict__ accp, float* __restrict__ sp, int jspan)
{
    __shared__ unsigned short Wlds[64][72];
    int t = threadIdx.x;
    int i0 = blockIdx.x * 64;
    int jc = blockIdx.y;
    int w = t >> 6, l = t & 63;
    int m = l & 15, kgrp = l >> 4;
    int myrow = i0 + w * 16 + m;
    float fi = g1[myrow];
    const unsigned int* bmrow = bm + (long)myrow * (NN / 32);
    short8 ones;
#pragma unroll
    for (int i = 0; i < 8; ++i) ones[i] = (short)0x3F80;
    f32x4 acc[4];
#pragma unroll
    for (int i = 0; i < 4; ++i) acc[i] = (f32x4){0.f, 0.f, 0.f, 0.f};
    f32x4 accd = (f32x4){0.f, 0.f, 0.f, 0.f};

    for (int j0 = jc * jspan; j0 < (jc + 1) * jspan; j0 += 64) {
        unsigned long long wpair;
        __builtin_memcpy(&wpair, &bmrow[j0 >> 5], 8);
#pragma unroll
        for (int it = 0; it < 2; ++it) {
            int ci = it * 256 + t;
            int d = ci >> 3, c8 = (ci & 7) * 8;
            *(short8*)&Wlds[d][c8] = *(const short8*)&WhoT[(long)d * NN + j0 + c8];
        }
        short8 a0, a1;
        build_pfrag3(wpair, fi, g2 + j0, kgrp, a0, a1);
        __syncthreads();
        accd = __builtin_amdgcn_mfma_f32_16x16x32_bf16(a0, ones, accd, 0, 0, 0);
        accd = __builtin_amdgcn_mfma_f32_16x16x32_bf16(a1, ones, accd, 0, 0, 0);
#pragma unroll
        for (int dt = 0; dt < 4; ++dt) {
            short8 b0 = *(const short8*)&Wlds[dt * 16 + m][kgrp * 8];
            acc[dt] = __builtin_amdgcn_mfma_f32_16x16x32_bf16(a0, b0, acc[dt], 0, 0, 0);
        }
#pragma unroll
        for (int dt = 0; dt < 4; ++dt) {
            short8 b1 = *(const short8*)&Wlds[dt * 16 + m][32 + kgrp * 8];
            acc[dt] = __builtin_amdgcn_mfma_f32_16x16x32_bf16(a1, b1, acc[dt], 0, 0, 0);
        }
        __syncthreads();
    }
    if (m == 0) {
#pragma unroll
        for (int r = 0; r < 4; ++r)
            sp[(long)jc * NN + i0 + w * 16 + kgrp * 4 + r] = accd[r];
    }
    int mrow = w * 16 + kgrp * 4;
#pragma unroll
    for (int dt = 0; dt < 4; ++dt) {
        int d = dt * 16 + m;
#pragma unroll
        for (int r = 0; r < 4; ++r)
            accp[((long)jc * NN + i0 + mrow + r) * NCLS + d] = f2bf(acc[dt][r]);
    }
}

// ---------------------------------------------------------------- finalize (bf16 partials in, fp32 out)
__global__ __launch_bounds__(256) void finalize(
    const unsigned short* __restrict__ accp, const float* __restrict__ sp,
    float* __restrict__ out, int js)
{
    int t = threadIdx.x;
    int wv = t >> 6, l = t & 63;
    int r = blockIdx.x * 4 + wv;
    float v = 0.f, s = 0.f;
    for (int jc = 0; jc < js; ++jc) {
        v += bf2f(accp[((long)jc * NN + r) * NCLS + l]);
        s += sp[(long)jc * NN + r];
    }
    v /= fmaxf(s, 1e-20f);
    v = v > 0.f ? v : __expf(v) - 1.f;
    float m = v;
#pragma unroll
    for (int off = 32; off; off >>= 1) m = fmaxf(m, __shfl_xor(m, off));
    float ex = __expf(v - m);
#pragma unroll
    for (int off = 32; off; off >>= 1) ex += __shfl_xor(ex, off);
    out[(long)r * NCLS + l] = v - (m + __logf(ex));
}

// ---------------------------------------------------------------- launch
extern "C" void kernel_launch(void* const* d_in, const int* in_sizes, int n_in,
                              void* d_out, int out_size, void* d_ws, size_t ws_size,
                              hipStream_t stream)
{
    const float* x   = (const float*)d_in[0];
    const int*   adj = (const int*)d_in[1];
    const float* W   = (const float*)d_in[2];
    const float* a1  = (const float*)d_in[3];
    const float* a2  = (const float*)d_in[4];
    const float* Wo  = (const float*)d_in[5];
    const float* ao1 = (const float*)d_in[6];
    const float* ao2 = (const float*)d_in[7];
    float* out = (float*)d_out;

    const long SZ_XB   = (long)NN * NF * 2;
    const long SZ_AB   = (long)NHEADS * DH * 2;
    const long SZ_AOB  = (long)NCLS * 2;
    const long SZ_WT   = (long)NHEADS * DH * NF * 2;
    const long SZ_WOT  = (long)NCLS * NF * 2;
    const long SZ_WHT  = (long)NHEADS * DH * NN * 2;
    const long SZ_HCAT = (long)NN * NHEADS * DH * 2;
    const long SZ_WHOT = (long)NCLS * NN * 2;
    const long SZ_F    = (long)NHEADS * NN * 4;
    const long SZ_G    = (long)NN * 4;
    const long SZ_BM   = (long)NN * (NN / 32) * 4;
    const long SZ_AP1  = (long)NN * NHEADS * DH * 2;   // bf16 partials
    const long SZ_DS1  = (long)NHEADS * NN * 4;
    const long SZ_AP2  = (long)NN * NCLS * 2;          // bf16 partials
    const long SZ_SP2  = (long)NN * 4;
    long base = SZ_XB + 2 * SZ_AB + 2 * SZ_AOB + SZ_WT + SZ_WOT + SZ_WHT
              + SZ_HCAT + SZ_WHOT + 2 * SZ_F + 2 * SZ_G + SZ_BM
              + 40 * 256;

    int js1, js2;
    if ((size_t)(base + 4 * (SZ_AP1 + SZ_DS1) + 16 * (SZ_AP2 + SZ_SP2)) <= ws_size) {
        js1 = 4; js2 = 16;
    } else if ((size_t)(base + 4 * (SZ_AP1 + SZ_DS1) + 8 * (SZ_AP2 + SZ_SP2)) <= ws_size) {
        js1 = 4; js2 = 8;
    } else if ((size_t)(base + 2 * (SZ_AP1 + SZ_DS1) + 8 * (SZ_AP2 + SZ_SP2)) <= ws_size) {
        js1 = 2; js2 = 8;
    } else if ((size_t)(base + 16 * (SZ_AP2 + SZ_SP2)) <= ws_size) {
        js1 = 1; js2 = 16;
    } else if ((size_t)(base + 4 * (SZ_AP2 + SZ_SP2)) <= ws_size) {
        js1 = 1; js2 = 4;
    } else {
        diag_fill<<<dim3((out_size + 255) / 256), 256, 0, stream>>>(
            out, out_size, (float)(ws_size >> 20));
        return;
    }

    char* p = (char*)d_ws;
    auto alloc = [&](long bytes) { char* q = p; p += (bytes + 255) & ~255L; return q; };
    unsigned short* xB   = (unsigned short*)alloc(SZ_XB);
    unsigned short* a1B  = (unsigned short*)alloc(SZ_AB);
    unsigned short* a2B  = (unsigned short*)alloc(SZ_AB);
    unsigned short* ao1B = (unsigned short*)alloc(SZ_AOB);
    unsigned short* ao2B = (unsigned short*)alloc(SZ_AOB);
    unsigned short* WT   = (unsigned short*)alloc(SZ_WT);
    unsigned short* WoT  = (unsigned short*)alloc(SZ_WOT);
    unsigned short* WhT  = (unsigned short*)alloc(SZ_WHT);
    unsigned short* hcat = (unsigned short*)alloc(SZ_HCAT);
    unsigned short* WhoT = (unsigned short*)alloc(SZ_WHOT);
    float* f1 = (float*)alloc(SZ_F);
    float* f2 = (float*)alloc(SZ_F);
    float* g1 = (float*)alloc(SZ_G);
    float* g2 = (float*)alloc(SZ_G);
    unsigned int* bm = (unsigned int*)alloc(SZ_BM);
    unsigned short* accp2 = (unsigned short*)alloc(js2 * SZ_AP2);
    float* sp2   = (float*)alloc(js2 * SZ_SP2);
    unsigned short* accp1 = (unsigned short*)(js1 > 1 ? alloc(js1 * SZ_AP1) : nullptr);
    float* dsum1 = (float*)(js1 > 1 ? alloc(js1 * SZ_DS1) : nullptr);

    // 1. fused prep: bitmask + converts + transposes + f1/f2 zeroing
    prep<<<dim3(21698), 256, 0, stream>>>(
        x, adj, W, Wo, a1, a2, ao1, ao2,
        xB, bm, WT, WoT, a1B, a2B, ao1B, ao2B, f1);
    // 2. WhT = WT @ xB^T with fused f-scores (atomic)
    gemm1_fs<<<dim3(NN / 128, DH / 64, NHEADS), 256, 0, stream>>>(
        WT, xB, WhT, a1B, a2B, f1, f2);
    // 3. attention layer 1 (partials only; combine fused into gemm2c)
    if (js1 > 1) {
        attn1_part<<<dim3(NN / 64, NHEADS, js1), 256, 0, stream>>>(
            f1, f2, bm, WhT, accp1, dsum1, NN / js1);
    } else {
        attn1_direct<<<dim3(NN / 64, NHEADS), 256, 0, stream>>>(f1, f2, bm, WhT, hcat);
    }
    // 4. WhoT = WoT @ hcat^T with fused combine1 + g-scores
    gemm2c<<<dim3(NN / 64), 256, 0, stream>>>(
        WoT, accp1, dsum1, hcat, ao1B, ao2B, WhoT, g1, g2, js1);
    // 5. attention layer 2
    attn2<<<dim3(NN / 64, js2), 256, 0, stream>>>(g1, g2, bm, WhoT, accp2, sp2, NN / js2);
    // 6. finalize
    finalize<<<dim3(NN / 4), 256, 0, stream>>>(accp2, sp2, out, js2);
}

// Round 15
// 297.661 us; speedup vs baseline: 1.1329x; 1.1329x over previous
//
#include <hip/hip_runtime.h>
#include <hip/hip_bf16.h>

// GAT forward, MI355X. N=4096, NFEAT=1024, NHID=128, NHEADS=8, NCLASS=64.
// Inputs/outputs fp32 -> bf16 internally.
// Round 15: r13 structure restored (r14's combine1->gemm2c fusion regressed
// +37us: elementwise work serialized into a 64-block latency-bound kernel).
// Kept from r14: f1/f2 zeroing inside prep (memset dispatch removed).

#define NN    4096
#define NF    1024
#define DH    128
#define NHEADS 8
#define NCLS  64
#define ALPHA 0.2f
#define LOG2E 1.44269504f

using short8 = __attribute__((ext_vector_type(8))) short;
using f32x4  = __attribute__((ext_vector_type(4))) float;
using int4v  = __attribute__((ext_vector_type(4))) int;

static __device__ __forceinline__ float bf2f(unsigned short h) {
    return __uint_as_float(((unsigned int)h) << 16);
}
static __device__ __forceinline__ unsigned short f2bf(float f) {
    unsigned int u = __float_as_uint(f);
    u = (u + 0x7fffu + ((u >> 16) & 1u)) >> 16;
    return (unsigned short)u;
}
static __device__ __forceinline__ float fast_exp2(float x) {
    return __builtin_amdgcn_exp2f(x);
}

__global__ __launch_bounds__(256) void diag_fill(
    float* __restrict__ out, int n, float val)
{
    int i = blockIdx.x * 256 + threadIdx.x;
    if (i < n) out[i] = val;
}

// ---------------------------------------------------------------- prep (fused)
// [0,16384): bitmask; [16384,20480): x convert; [20480,21632): W/Wo transpose;
// 21632: a1/a2; 21633: ao1/ao2; [21634,21698): zero f1/f2 (256KB)
__global__ __launch_bounds__(256) void prep(
    const float* __restrict__ x, const int* __restrict__ adj,
    const float* __restrict__ W, const float* __restrict__ Wo,
    const float* __restrict__ a1, const float* __restrict__ a2,
    const float* __restrict__ ao1, const float* __restrict__ ao2,
    unsigned short* __restrict__ xB, unsigned int* __restrict__ bm,
    unsigned short* __restrict__ WT, unsigned short* __restrict__ WoT,
    unsigned short* __restrict__ a1B, unsigned short* __restrict__ a2B,
    unsigned short* __restrict__ ao1B, unsigned short* __restrict__ ao2B,
    float* __restrict__ f1z)
{
    __shared__ unsigned short tile[32][33];
    int b = blockIdx.x, t = threadIdx.x;
    if (b < 16384) {                       // bitmask (int4 + shfl-OR)
        long t4 = (long)b * 256 + t;
        int4v v = ((const int4v*)adj)[t4];
        unsigned nib = (v[0] > 0 ? 1u : 0u) | (v[1] > 0 ? 2u : 0u)
                     | (v[2] > 0 ? 4u : 0u) | (v[3] > 0 ? 8u : 0u);
        int l = t & 63;
        unsigned w = nib << (4 * (l & 7));
        w |= __shfl_xor(w, 1);
        w |= __shfl_xor(w, 2);
        w |= __shfl_xor(w, 4);
        if ((l & 7) == 0) bm[t4 >> 3] = w;
    } else if (b < 20480) {                // x fp32 -> bf16 (float4/thread)
        long i = ((long)(b - 16384) * 256 + t) * 4;
        float4 v = *(const float4*)&x[i];
        unsigned u0 = (unsigned)f2bf(v.x) | ((unsigned)f2bf(v.y) << 16);
        unsigned u1 = (unsigned)f2bf(v.z) | ((unsigned)f2bf(v.w) << 16);
        uint2 u; u.x = u0; u.y = u1;
        *(uint2*)&xB[i] = u;
    } else if (b < 21632) {                // transpose+convert W (z<8) / Wo (z=8)
        int tid = b - 20480;
        int z = tid >> 7;
        int rem = tid & 127;
        int bx = rem & 3, by = rem >> 2;
        const float* in; unsigned short* out; int C;
        if (z < 8) { in = W + (long)z * NF * DH; out = WT + (long)z * DH * NF; C = DH; }
        else       { in = Wo;                    out = WoT;                    C = NCLS; }
        int x0 = bx * 32, y0 = by * 32;
        if (x0 >= C) return;
        int tx = t & 31, ty = t >> 5;
        for (int yy = 0; yy < 32; yy += 8)
            tile[ty + yy][tx] = f2bf(in[(long)(y0 + ty + yy) * C + x0 + tx]);
        __syncthreads();
        for (int yy = 0; yy < 32; yy += 8)
            out[(long)(x0 + ty + yy) * NF + y0 + tx] = tile[tx][ty + yy];
    } else if (b == 21632) {
        for (int i = t; i < NHEADS * DH; i += 256) {
            a1B[i] = f2bf(a1[i]);
            a2B[i] = f2bf(a2[i]);
        }
    } else if (b == 21633) {
        if (t < NCLS) {
            ao1B[t] = f2bf(ao1[t]);
            ao2B[t] = f2bf(ao2[t]);
        }
    } else {                               // zero f1/f2: 64 blocks x 1024 floats
        long i = ((long)(b - 21634) * 256 + t) * 4;
        *(float4*)&f1z[i] = (float4){0.f, 0.f, 0.f, 0.f};
    }
}

// ---------------------------------------------------------------- gemm1 + fused f-scores (r11 verbatim)
__global__ __launch_bounds__(256) void gemm1_fs(
    const unsigned short* __restrict__ A, const unsigned short* __restrict__ Bt,
    unsigned short* __restrict__ Cc, const unsigned short* __restrict__ a1B,
    const unsigned short* __restrict__ a2B, float* __restrict__ f1,
    float* __restrict__ f2)
{
    __shared__ unsigned short Alds[64][72];
    __shared__ unsigned short Blds[128][72];
    __shared__ float s1l[128], s2l[128];
    int t = threadIdx.x;
    int w = t >> 6, l = t & 63;
    int h = blockIdx.z;
    long aoff = (long)h * DH * NF + (long)blockIdx.y * 64 * NF;
    long boff = (long)blockIdx.x * 128 * NF;
    if (t < 128) { s1l[t] = 0.f; s2l[t] = 0.f; }
    f32x4 acc[8];
#pragma unroll
    for (int i = 0; i < 8; ++i) acc[i] = (f32x4){0.f, 0.f, 0.f, 0.f};

    for (int k0 = 0; k0 < NF; k0 += 64) {
#pragma unroll
        for (int it = 0; it < 2; ++it) {
            int ci = it * 256 + t;
            int r = ci >> 3, c8 = (ci & 7) * 8;
            *(short8*)&Alds[r][c8] = *(const short8*)&A[aoff + (long)r * NF + k0 + c8];
        }
#pragma unroll
        for (int it = 0; it < 4; ++it) {
            int ci = it * 256 + t;
            int r = ci >> 3, c8 = (ci & 7) * 8;
            *(short8*)&Blds[r][c8] = *(const short8*)&Bt[boff + (long)r * NF + k0 + c8];
        }
        __syncthreads();
        int arow = w * 16 + (l & 15);
        int koff = (l >> 4) * 8;
#pragma unroll
        for (int kc = 0; kc < 2; ++kc) {
            short8 af = *(const short8*)&Alds[arow][kc * 32 + koff];
#pragma unroll
            for (int dt = 0; dt < 8; ++dt) {
                short8 bf = *(const short8*)&Blds[dt * 16 + (l & 15)][kc * 32 + koff];
                acc[dt] = __builtin_amdgcn_mfma_f32_16x16x32_bf16(af, bf, acc[dt], 0, 0, 0);
            }
        }
        __syncthreads();
    }
    long coff = (long)h * DH * NN + ((long)blockIdx.y * 64) * NN + blockIdx.x * 128;
    int mrow = w * 16 + (l >> 4) * 4;
    int dbase = blockIdx.y * 64;
#pragma unroll
    for (int dt = 0; dt < 8; ++dt) {
        int n = dt * 16 + (l & 15);
        float p1 = 0.f, p2 = 0.f;
#pragma unroll
        for (int r = 0; r < 4; ++r) {
            unsigned short bw = f2bf(acc[dt][r]);
            Cc[coff + (long)(mrow + r) * NN + n] = bw;
            float vf = bf2f(bw);
            int d = dbase + mrow + r;
            p1 += vf * bf2f(a1B[h * DH + d]);
            p2 += vf * bf2f(a2B[h * DH + d]);
        }
        atomicAdd(&s1l[n], p1);
        atomicAdd(&s2l[n], p2);
    }
    __syncthreads();
    if (t < 128) {
        int n = blockIdx.x * 128 + t;
        atomicAdd(&f1[h * NN + n], s1l[t] * LOG2E);
        atomicAdd(&f2[h * NN + n], s2l[t] * LOG2E);
    }
}

// ---------------------------------------------------------------- gemm2 + fused combinew (r13 verbatim, LDS-staged)
__global__ __launch_bounds__(256) void gemm2c(
    const unsigned short* __restrict__ A, const unsigned short* __restrict__ Bt,
    const unsigned short* __restrict__ ao1B, const unsigned short* __restrict__ ao2B,
    unsigned short* __restrict__ WhoT, float* __restrict__ g1, float* __restrict__ g2)
{
    __shared__ unsigned short Alds[64][72];
    __shared__ unsigned short Blds[64][72];
    __shared__ float s1l[64], s2l[64];
    int t = threadIdx.x;
    int w = t >> 6, l = t & 63;
    int n0 = blockIdx.x * 64;
    if (t < 64) { s1l[t] = 0.f; s2l[t] = 0.f; }
    f32x4 acc[4];
#pragma unroll
    for (int i = 0; i < 4; ++i) acc[i] = (f32x4){0.f, 0.f, 0.f, 0.f};

    for (int k0 = 0; k0 < NF; k0 += 64) {
#pragma unroll
        for (int it = 0; it < 2; ++it) {
            int ci = it * 256 + t;
            int r = ci >> 3, c8 = (ci & 7) * 8;
            *(short8*)&Alds[r][c8] = *(const short8*)&A[(long)r * NF + k0 + c8];
        }
#pragma unroll
        for (int it = 0; it < 2; ++it) {
            int ci = it * 256 + t;
            int r = ci >> 3, c8 = (ci & 7) * 8;
            *(short8*)&Blds[r][c8] = *(const short8*)&Bt[(long)(n0 + r) * NF + k0 + c8];
        }
        __syncthreads();
        int arow = w * 16 + (l & 15);
        int koff = (l >> 4) * 8;
#pragma unroll
        for (int kc = 0; kc < 2; ++kc) {
            short8 af = *(const short8*)&Alds[arow][kc * 32 + koff];
#pragma unroll
            for (int dt = 0; dt < 4; ++dt) {
                short8 bf = *(const short8*)&Blds[dt * 16 + (l & 15)][kc * 32 + koff];
                acc[dt] = __builtin_amdgcn_mfma_f32_16x16x32_bf16(af, bf, acc[dt], 0, 0, 0);
            }
        }
        __syncthreads();
    }
    int mrow = w * 16 + (l >> 4) * 4;
#pragma unroll
    for (int dt = 0; dt < 4; ++dt) {
        int nl = dt * 16 + (l & 15);
        float p1 = 0.f, p2 = 0.f;
#pragma unroll
        for (int r = 0; r < 4; ++r) {
            int c = mrow + r;
            unsigned short bw = f2bf(acc[dt][r]);
            WhoT[(long)c * NN + n0 + nl] = bw;
            float vf = bf2f(bw);
            p1 += vf * bf2f(ao1B[c]);
            p2 += vf * bf2f(ao2B[c]);
        }
        atomicAdd(&s1l[nl], p1);
        atomicAdd(&s2l[nl], p2);
    }
    __syncthreads();
    if (t < 64) {
        g1[n0 + t] = s1l[t] * LOG2E;
        g2[n0 + t] = s2l[t] * LOG2E;
    }
}

// ------------------------------------------ legacy P-tile builder (fallback; exp2 domain)
static __device__ __forceinline__ float build_p16(
    unsigned int bits, float fi, const float* f2s, int pc0,
    short8& p0, short8& p1)
{
    float lsum = 0.f;
#pragma unroll
    for (int cc = 0; cc < 16; ++cc) {
        float wgt = 0.f;
        if ((bits >> cc) & 1u) {
            float e = fi + f2s[pc0 + cc];
            e = e > 0.f ? e : ALPHA * e;
            e = fminf(e, 60.f);
            wgt = fast_exp2(e);
        }
        unsigned short bw = f2bf(wgt);
        lsum += bf2f(bw);
        if (cc < 8) p0[cc] = (short)bw;
        else        p1[cc - 8] = (short)bw;
    }
    return lsum;
}

// ------------------------------------------ register A-fragment builder v3
static __device__ __forceinline__ void build_pfrag3(
    unsigned long long wpair, float fi, const float* __restrict__ f2g,
    int kgrp, short8& a0, short8& a1)
{
    int4v av0, av1;
#pragma unroll
    for (int kc = 0; kc < 2; ++kc) {
        unsigned bits = (unsigned)(wpair >> (kc * 32 + kgrp * 8)) & 0xFFu;
        const float4* fp = (const float4*)(f2g + kc * 32 + kgrp * 8);
        float4 fv0 = fp[0], fv1 = fp[1];
        float ev[8] = {fv0.x, fv0.y, fv0.z, fv0.w, fv1.x, fv1.y, fv1.z, fv1.w};
#pragma unroll
        for (int jj = 0; jj < 8; jj += 2) {
            float e0 = fi + ev[jj], e1 = fi + ev[jj + 1];
            e0 = fmaxf(e0, ALPHA * e0);
            e1 = fmaxf(e1, ALPHA * e1);
            float w0 = fast_exp2(e0), w1 = fast_exp2(e1);
            w0 = ((bits >> jj) & 1u) ? w0 : 0.f;
            w1 = ((bits >> (jj + 1)) & 1u) ? w1 : 0.f;
            float2 fv; fv.x = w0; fv.y = w1;
            __hip_bfloat162 pk = __float22bfloat162_rn(fv);
            unsigned pu; __builtin_memcpy(&pu, &pk, 4);
            if (kc == 0) av0[jj >> 1] = (int)pu;
            else         av1[jj >> 1] = (int)pu;
        }
    }
    a0 = __builtin_bit_cast(short8, av0);
    a1 = __builtin_bit_cast(short8, av1);
}

// ---------------------------------------------------------------- attn1 direct (ws fallback)
__global__ __launch_bounds__(256) void attn1_direct(
    const float* __restrict__ f1, const float* __restrict__ f2,
    const unsigned int* __restrict__ bm, const unsigned short* __restrict__ WhT,
    unsigned short* __restrict__ hcat)
{
    __shared__ unsigned short Plds[64][72];
    __shared__ unsigned short Wlds[128][72];
    __shared__ float f1s[64], f2s[64], ssum[64][4], srow[64];
    int t = threadIdx.x;
    int h = blockIdx.y;
    int i0 = blockIdx.x * 64;
    int w = t >> 6, l = t & 63;
    if (t < 64) f1s[t] = f1[h * NN + i0 + t];
    f32x4 acc[8];
#pragma unroll
    for (int i = 0; i < 8; ++i) acc[i] = (f32x4){0.f, 0.f, 0.f, 0.f};
    float psum = 0.f;
    int pr = t >> 2, pc0 = (t & 3) * 16;
    const unsigned short* Wh_h = WhT + (long)h * DH * NN;

    for (int j0 = 0; j0 < NN; j0 += 64) {
        if (t < 64) f2s[t] = f2[h * NN + j0 + t];
        __syncthreads();
        {
            unsigned int word = bm[(long)(i0 + pr) * (NN / 32) + (j0 >> 5) + ((pc0 >> 5) & 1)];
            unsigned int bits = (word >> (pc0 & 16)) & 0xFFFFu;
            short8 p0, p1;
            psum += build_p16(bits, f1s[pr], f2s, pc0, p0, p1);
            *(short8*)&Plds[pr][pc0]     = p0;
            *(short8*)&Plds[pr][pc0 + 8] = p1;
        }
#pragma unroll
        for (int it = 0; it < 4; ++it) {
            int ci = it * 256 + t;
            int d = ci >> 3, c8 = (ci & 7) * 8;
            *(short8*)&Wlds[d][c8] = *(const short8*)&Wh_h[(long)d * NN + j0 + c8];
        }
        __syncthreads();
        int arow = w * 16 + (l & 15);
        int koff = (l >> 4) * 8;
#pragma unroll
        for (int kc = 0; kc < 2; ++kc) {
            short8 af = *(const short8*)&Plds[arow][kc * 32 + koff];
#pragma unroll
            for (int dt = 0; dt < 8; ++dt) {
                short8 bf = *(const short8*)&Wlds[dt * 16 + (l & 15)][kc * 32 + koff];
                acc[dt] = __builtin_amdgcn_mfma_f32_16x16x32_bf16(af, bf, acc[dt], 0, 0, 0);
            }
        }
        __syncthreads();
    }
    ssum[pr][t & 3] = psum;
    __syncthreads();
    if (t < 64) srow[t] = ssum[t][0] + ssum[t][1] + ssum[t][2] + ssum[t][3];
    __syncthreads();
    int mrow = w * 16 + (l >> 4) * 4;
#pragma unroll
    for (int dt = 0; dt < 8; ++dt) {
        int d = dt * 16 + (l & 15);
#pragma unroll
        for (int r = 0; r < 4; ++r) {
            float v = acc[dt][r] / fmaxf(srow[mrow + r], 1e-20f);
            v = v > 0.f ? v : __expf(v) - 1.f;
            hcat[(long)(i0 + mrow + r) * (NHEADS * DH) + h * DH + d] = f2bf(v);
        }
    }
}

// ---------------------------------------------------------------- attn1 j-split (r13 verbatim)
__global__ __launch_bounds__(256) void attn1_part(
    const float* __restrict__ f1, const float* __restrict__ f2,
    const unsigned int* __restrict__ bm, const unsigned short* __restrict__ WhT,
    unsigned short* __restrict__ accp1, float* __restrict__ dsum1, int jspan)
{
    __shared__ unsigned short Wlds[128][72];
    int t = threadIdx.x;
    int h = blockIdx.y;
    int i0 = blockIdx.x * 64;
    int jz = blockIdx.z;
    int w = t >> 6, l = t & 63;
    int m = l & 15, kgrp = l >> 4;
    int myrow = i0 + w * 16 + m;
    float fi = f1[h * NN + myrow];
    const unsigned int* bmrow = bm + (long)myrow * (NN / 32);
    const float* f2h = f2 + (long)h * NN;
    const unsigned short* Wh_h = WhT + (long)h * DH * NN;
    short8 ones;
#pragma unroll
    for (int i = 0; i < 8; ++i) ones[i] = (short)0x3F80;   // bf16 1.0
    f32x4 acc[8];
#pragma unroll
    for (int i = 0; i < 8; ++i) acc[i] = (f32x4){0.f, 0.f, 0.f, 0.f};
    f32x4 accd = (f32x4){0.f, 0.f, 0.f, 0.f};

    for (int j0 = jz * jspan; j0 < (jz + 1) * jspan; j0 += 64) {
        unsigned long long wpair;
        __builtin_memcpy(&wpair, &bmrow[j0 >> 5], 8);
#pragma unroll
        for (int it = 0; it < 4; ++it) {          // stage Wh tile [128 d][64 j]
            int ci = it * 256 + t;
            int d = ci >> 3, c8 = (ci & 7) * 8;
            *(short8*)&Wlds[d][c8] = *(const short8*)&Wh_h[(long)d * NN + j0 + c8];
        }
        short8 a0, a1;
        build_pfrag3(wpair, fi, f2h + j0, kgrp, a0, a1);
        __syncthreads();
        accd = __builtin_amdgcn_mfma_f32_16x16x32_bf16(a0, ones, accd, 0, 0, 0);
        accd = __builtin_amdgcn_mfma_f32_16x16x32_bf16(a1, ones, accd, 0, 0, 0);
#pragma unroll
        for (int dt = 0; dt < 8; ++dt) {
            short8 b0 = *(const short8*)&Wlds[dt * 16 + m][kgrp * 8];
            acc[dt] = __builtin_amdgcn_mfma_f32_16x16x32_bf16(a0, b0, acc[dt], 0, 0, 0);
        }
#pragma unroll
        for (int dt = 0; dt < 8; ++dt) {
            short8 b1 = *(const short8*)&Wlds[dt * 16 + m][32 + kgrp * 8];
            acc[dt] = __builtin_amdgcn_mfma_f32_16x16x32_bf16(a1, b1, acc[dt], 0, 0, 0);
        }
        __syncthreads();
    }
    if (m == 0) {
#pragma unroll
        for (int r = 0; r < 4; ++r)
            dsum1[((long)jz * NHEADS + h) * NN + i0 + w * 16 + kgrp * 4 + r] = accd[r];
    }
    int mrow = w * 16 + kgrp * 4;
#pragma unroll
    for (int dt = 0; dt < 8; ++dt) {
        int d = dt * 16 + m;
#pragma unroll
        for (int r = 0; r < 4; ++r)
            accp1[((long)jz * NN + i0 + mrow + r) * (NHEADS * DH) + h * DH + d] = f2bf(acc[dt][r]);
    }
}

// combine attn1 partials -> hcat (bf16x4 per thread, r13 verbatim)
__global__ __launch_bounds__(256) void combine1(
    const unsigned short* __restrict__ accp1, const float* __restrict__ dsum1,
    unsigned short* __restrict__ hcat, int js)
{
    long idx4 = (long)blockIdx.x * 256 + threadIdx.x;
    int i = (int)(idx4 >> 8), c4 = (int)(idx4 & 255) * 4, h = c4 >> 7;
    float4 v = {0.f, 0.f, 0.f, 0.f};
    float s = 0.f;
    for (int jz = 0; jz < js; ++jz) {
        uint2 pv = *(const uint2*)&accp1[((long)jz * NN + i) * (NHEADS * DH) + c4];
        v.x += bf2f((unsigned short)(pv.x & 0xFFFFu));
        v.y += bf2f((unsigned short)(pv.x >> 16));
        v.z += bf2f((unsigned short)(pv.y & 0xFFFFu));
        v.w += bf2f((unsigned short)(pv.y >> 16));
        s += dsum1[((long)jz * NHEADS + h) * NN + i];
    }
    float inv = 1.f / fmaxf(s, 1e-20f);
    float o[4] = {v.x * inv, v.y * inv, v.z * inv, v.w * inv};
#pragma unroll
    for (int k = 0; k < 4; ++k) o[k] = o[k] > 0.f ? o[k] : __expf(o[k]) - 1.f;
    unsigned u0 = (unsigned)f2bf(o[0]) | ((unsigned)f2bf(o[1]) << 16);
    unsigned u1 = (unsigned)f2bf(o[2]) | ((unsigned)f2bf(o[3]) << 16);
    uint2 u; u.x = u0; u.y = u1;
    *(uint2*)&hcat[(long)i * (NHEADS * DH) + c4] = u;
}

// ---------------------------------------------------------------- attn2 (r13 verbatim)
__global__ __launch_bounds__(256) void attn2(
    const float* __restrict__ g1, const float* __restrict__ g2,
    const unsigned int* __restrict__ bm, const unsigned short* __restrict__ WhoT,
    unsigned short* __restrict__ accp, float* __restrict__ sp, int jspan)
{
    __shared__ unsigned short Wlds[64][72];
    int t = threadIdx.x;
    int i0 = blockIdx.x * 64;
    int jc = blockIdx.y;
    int w = t >> 6, l = t & 63;
    int m = l & 15, kgrp = l >> 4;
    int myrow = i0 + w * 16 + m;
    float fi = g1[myrow];
    const unsigned int* bmrow = bm + (long)myrow * (NN / 32);
    short8 ones;
#pragma unroll
    for (int i = 0; i < 8; ++i) ones[i] = (short)0x3F80;
    f32x4 acc[4];
#pragma unroll
    for (int i = 0; i < 4; ++i) acc[i] = (f32x4){0.f, 0.f, 0.f, 0.f};
    f32x4 accd = (f32x4){0.f, 0.f, 0.f, 0.f};

    for (int j0 = jc * jspan; j0 < (jc + 1) * jspan; j0 += 64) {
        unsigned long long wpair;
        __builtin_memcpy(&wpair, &bmrow[j0 >> 5], 8);
#pragma unroll
        for (int it = 0; it < 2; ++it) {
            int ci = it * 256 + t;
            int d = ci >> 3, c8 = (ci & 7) * 8;
            *(short8*)&Wlds[d][c8] = *(const short8*)&WhoT[(long)d * NN + j0 + c8];
        }
        short8 a0, a1;
        build_pfrag3(wpair, fi, g2 + j0, kgrp, a0, a1);
        __syncthreads();
        accd = __builtin_amdgcn_mfma_f32_16x16x32_bf16(a0, ones, accd, 0, 0, 0);
        accd = __builtin_amdgcn_mfma_f32_16x16x32_bf16(a1, ones, accd, 0, 0, 0);
#pragma unroll
        for (int dt = 0; dt < 4; ++dt) {
            short8 b0 = *(const short8*)&Wlds[dt * 16 + m][kgrp * 8];
            acc[dt] = __builtin_amdgcn_mfma_f32_16x16x32_bf16(a0, b0, acc[dt], 0, 0, 0);
        }
#pragma unroll
        for (int dt = 0; dt < 4; ++dt) {
            short8 b1 = *(const short8*)&Wlds[dt * 16 + m][32 + kgrp * 8];
            acc[dt] = __builtin_amdgcn_mfma_f32_16x16x32_bf16(a1, b1, acc[dt], 0, 0, 0);
        }
        __syncthreads();
    }
    if (m == 0) {
#pragma unroll
        for (int r = 0; r < 4; ++r)
            sp[(long)jc * NN + i0 + w * 16 + kgrp * 4 + r] = accd[r];
    }
    int mrow = w * 16 + kgrp * 4;
#pragma unroll
    for (int dt = 0; dt < 4; ++dt) {
        int d = dt * 16 + m;
#pragma unroll
        for (int r = 0; r < 4; ++r)
            accp[((long)jc * NN + i0 + mrow + r) * NCLS + d] = f2bf(acc[dt][r]);
    }
}

// ---------------------------------------------------------------- finalize (bf16 partials in, fp32 out)
__global__ __launch_bounds__(256) void finalize(
    const unsigned short* __restrict__ accp, const float* __restrict__ sp,
    float* __restrict__ out, int js)
{
    int t = threadIdx.x;
    int wv = t >> 6, l = t & 63;
    int r = blockIdx.x * 4 + wv;
    float v = 0.f, s = 0.f;
    for (int jc = 0; jc < js; ++jc) {
        v += bf2f(accp[((long)jc * NN + r) * NCLS + l]);
        s += sp[(long)jc * NN + r];
    }
    v /= fmaxf(s, 1e-20f);
    v = v > 0.f ? v : __expf(v) - 1.f;
    float m = v;
#pragma unroll
    for (int off = 32; off; off >>= 1) m = fmaxf(m, __shfl_xor(m, off));
    float ex = __expf(v - m);
#pragma unroll
    for (int off = 32; off; off >>= 1) ex += __shfl_xor(ex, off);
    out[(long)r * NCLS + l] = v - (m + __logf(ex));
}

// ---------------------------------------------------------------- launch
extern "C" void kernel_launch(void* const* d_in, const int* in_sizes, int n_in,
                              void* d_out, int out_size, void* d_ws, size_t ws_size,
                              hipStream_t stream)
{
    const float* x   = (const float*)d_in[0];
    const int*   adj = (const int*)d_in[1];
    const float* W   = (const float*)d_in[2];
    const float* a1  = (const float*)d_in[3];
    const float* a2  = (const float*)d_in[4];
    const float* Wo  = (const float*)d_in[5];
    const float* ao1 = (const float*)d_in[6];
    const float* ao2 = (const float*)d_in[7];
    float* out = (float*)d_out;

    const long SZ_XB   = (long)NN * NF * 2;
    const long SZ_AB   = (long)NHEADS * DH * 2;
    const long SZ_AOB  = (long)NCLS * 2;
    const long SZ_WT   = (long)NHEADS * DH * NF * 2;
    const long SZ_WOT  = (long)NCLS * NF * 2;
    const long SZ_WHT  = (long)NHEADS * DH * NN * 2;
    const long SZ_HCAT = (long)NN * NHEADS * DH * 2;
    const long SZ_WHOT = (long)NCLS * NN * 2;
    const long SZ_F    = (long)NHEADS * NN * 4;
    const long SZ_G    = (long)NN * 4;
    const long SZ_BM   = (long)NN * (NN / 32) * 4;
    const long SZ_AP1  = (long)NN * NHEADS * DH * 2;   // bf16 partials
    const long SZ_DS1  = (long)NHEADS * NN * 4;
    const long SZ_AP2  = (long)NN * NCLS * 2;          // bf16 partials
    const long SZ_SP2  = (long)NN * 4;
    long base = SZ_XB + 2 * SZ_AB + 2 * SZ_AOB + SZ_WT + SZ_WOT + SZ_WHT
              + SZ_HCAT + SZ_WHOT + 2 * SZ_F + 2 * SZ_G + SZ_BM
              + 40 * 256;

    int js1, js2;
    if ((size_t)(base + 4 * (SZ_AP1 + SZ_DS1) + 16 * (SZ_AP2 + SZ_SP2)) <= ws_size) {
        js1 = 4; js2 = 16;
    } else if ((size_t)(base + 4 * (SZ_AP1 + SZ_DS1) + 8 * (SZ_AP2 + SZ_SP2)) <= ws_size) {
        js1 = 4; js2 = 8;
    } else if ((size_t)(base + 2 * (SZ_AP1 + SZ_DS1) + 8 * (SZ_AP2 + SZ_SP2)) <= ws_size) {
        js1 = 2; js2 = 8;
    } else if ((size_t)(base + 16 * (SZ_AP2 + SZ_SP2)) <= ws_size) {
        js1 = 1; js2 = 16;
    } else if ((size_t)(base + 4 * (SZ_AP2 + SZ_SP2)) <= ws_size) {
        js1 = 1; js2 = 4;
    } else {
        diag_fill<<<dim3((out_size + 255) / 256), 256, 0, stream>>>(
            out, out_size, (float)(ws_size >> 20));
        return;
    }

    char* p = (char*)d_ws;
    auto alloc = [&](long bytes) { char* q = p; p += (bytes + 255) & ~255L; return q; };
    unsigned short* xB   = (unsigned short*)alloc(SZ_XB);
    unsigned short* a1B  = (unsigned short*)alloc(SZ_AB);
    unsigned short* a2B  = (unsigned short*)alloc(SZ_AB);
    unsigned short* ao1B = (unsigned short*)alloc(SZ_AOB);
    unsigned short* ao2B = (unsigned short*)alloc(SZ_AOB);
    unsigned short* WT   = (unsigned short*)alloc(SZ_WT);
    unsigned short* WoT  = (unsigned short*)alloc(SZ_WOT);
    unsigned short* WhT  = (unsigned short*)alloc(SZ_WHT);
    unsigned short* hcat = (unsigned short*)alloc(SZ_HCAT);
    unsigned short* WhoT = (unsigned short*)alloc(SZ_WHOT);
    float* f1 = (float*)alloc(SZ_F);
    float* f2 = (float*)alloc(SZ_F);
    float* g1 = (float*)alloc(SZ_G);
    float* g2 = (float*)alloc(SZ_G);
    unsigned int* bm = (unsigned int*)alloc(SZ_BM);
    unsigned short* accp2 = (unsigned short*)alloc(js2 * SZ_AP2);
    float* sp2   = (float*)alloc(js2 * SZ_SP2);
    unsigned short* accp1 = (unsigned short*)(js1 > 1 ? alloc(js1 * SZ_AP1) : nullptr);
    float* dsum1 = (float*)(js1 > 1 ? alloc(js1 * SZ_DS1) : nullptr);

    // 1. fused prep: bitmask + converts + transposes + f1/f2 zeroing
    prep<<<dim3(21698), 256, 0, stream>>>(
        x, adj, W, Wo, a1, a2, ao1, ao2,
        xB, bm, WT, WoT, a1B, a2B, ao1B, ao2B, f1);
    // 2. WhT = WT @ xB^T with fused f-scores (atomic)
    gemm1_fs<<<dim3(NN / 128, DH / 64, NHEADS), 256, 0, stream>>>(
        WT, xB, WhT, a1B, a2B, f1, f2);
    // 3. attention layer 1
    if (js1 > 1) {
        attn1_part<<<dim3(NN / 64, NHEADS, js1), 256, 0, stream>>>(
            f1, f2, bm, WhT, accp1, dsum1, NN / js1);
        combine1<<<dim3((int)(((long)NN * NHEADS * DH) / 1024)), 256, 0, stream>>>(
            accp1, dsum1, hcat, js1);
    } else {
        attn1_direct<<<dim3(NN / 64, NHEADS), 256, 0, stream>>>(f1, f2, bm, WhT, hcat);
    }
    // 4. WhoT = WoT @ hcat^T with fused g-scores
    gemm2c<<<dim3(NN / 64), 256, 0, stream>>>(WoT, hcat, ao1B, ao2B, WhoT, g1, g2);
    // 5. attention layer 2
    attn2<<<dim3(NN / 64, js2), 256, 0, stream>>>(g1, g2, bm, WhoT, accp2, sp2, NN / js2);
    // 6. finalize
    finalize<<<dim3(NN / 4), 256, 0, stream>>>(accp2, sp2, out, js2);
}

// Round 16
// 293.285 us; speedup vs baseline: 1.1498x; 1.0149x over previous
//
#include <hip/hip_runtime.h>
#include <hip/hip_bf16.h>

// GAT forward, MI355X. N=4096, NFEAT=1024, NHID=128, NHEADS=8, NCLASS=64.
// Inputs/outputs fp32 -> bf16 internally.
// Round 16: r15 + attn1 BK=128 (two j-tiles staged per barrier pair ->
// barrier count halved; LDS 18.4->34.8KB, still >= measured 3.35 blk/CU;
// accumulators unchanged so no r10-style VGPR cliff). Rest r15-verbatim.

#define NN    4096
#define NF    1024
#define DH    128
#define NHEADS 8
#define NCLS  64
#define ALPHA 0.2f
#define LOG2E 1.44269504f

using short8 = __attribute__((ext_vector_type(8))) short;
using f32x4  = __attribute__((ext_vector_type(4))) float;
using int4v  = __attribute__((ext_vector_type(4))) int;

static __device__ __forceinline__ float bf2f(unsigned short h) {
    return __uint_as_float(((unsigned int)h) << 16);
}
static __device__ __forceinline__ unsigned short f2bf(float f) {
    unsigned int u = __float_as_uint(f);
    u = (u + 0x7fffu + ((u >> 16) & 1u)) >> 16;
    return (unsigned short)u;
}
static __device__ __forceinline__ float fast_exp2(float x) {
    return __builtin_amdgcn_exp2f(x);
}

__global__ __launch_bounds__(256) void diag_fill(
    float* __restrict__ out, int n, float val)
{
    int i = blockIdx.x * 256 + threadIdx.x;
    if (i < n) out[i] = val;
}

// ---------------------------------------------------------------- prep (fused, r15 verbatim)
__global__ __launch_bounds__(256) void prep(
    const float* __restrict__ x, const int* __restrict__ adj,
    const float* __restrict__ W, const float* __restrict__ Wo,
    const float* __restrict__ a1, const float* __restrict__ a2,
    const float* __restrict__ ao1, const float* __restrict__ ao2,
    unsigned short* __restrict__ xB, unsigned int* __restrict__ bm,
    unsigned short* __restrict__ WT, unsigned short* __restrict__ WoT,
    unsigned short* __restrict__ a1B, unsigned short* __restrict__ a2B,
    unsigned short* __restrict__ ao1B, unsigned short* __restrict__ ao2B,
    float* __restrict__ f1z)
{
    __shared__ unsigned short tile[32][33];
    int b = blockIdx.x, t = threadIdx.x;
    if (b < 16384) {                       // bitmask (int4 + shfl-OR)
        long t4 = (long)b * 256 + t;
        int4v v = ((const int4v*)adj)[t4];
        unsigned nib = (v[0] > 0 ? 1u : 0u) | (v[1] > 0 ? 2u : 0u)
                     | (v[2] > 0 ? 4u : 0u) | (v[3] > 0 ? 8u : 0u);
        int l = t & 63;
        unsigned w = nib << (4 * (l & 7));
        w |= __shfl_xor(w, 1);
        w |= __shfl_xor(w, 2);
        w |= __shfl_xor(w, 4);
        if ((l & 7) == 0) bm[t4 >> 3] = w;
    } else if (b < 20480) {                // x fp32 -> bf16 (float4/thread)
        long i = ((long)(b - 16384) * 256 + t) * 4;
        float4 v = *(const float4*)&x[i];
        unsigned u0 = (unsigned)f2bf(v.x) | ((unsigned)f2bf(v.y) << 16);
        unsigned u1 = (unsigned)f2bf(v.z) | ((unsigned)f2bf(v.w) << 16);
        uint2 u; u.x = u0; u.y = u1;
        *(uint2*)&xB[i] = u;
    } else if (b < 21632) {                // transpose+convert W (z<8) / Wo (z=8)
        int tid = b - 20480;
        int z = tid >> 7;
        int rem = tid & 127;
        int bx = rem & 3, by = rem >> 2;
        const float* in; unsigned short* out; int C;
        if (z < 8) { in = W + (long)z * NF * DH; out = WT + (long)z * DH * NF; C = DH; }
        else       { in = Wo;                    out = WoT;                    C = NCLS; }
        int x0 = bx * 32, y0 = by * 32;
        if (x0 >= C) return;
        int tx = t & 31, ty = t >> 5;
        for (int yy = 0; yy < 32; yy += 8)
            tile[ty + yy][tx] = f2bf(in[(long)(y0 + ty + yy) * C + x0 + tx]);
        __syncthreads();
        for (int yy = 0; yy < 32; yy += 8)
            out[(long)(x0 + ty + yy) * NF + y0 + tx] = tile[tx][ty + yy];
    } else if (b == 21632) {
        for (int i = t; i < NHEADS * DH; i += 256) {
            a1B[i] = f2bf(a1[i]);
            a2B[i] = f2bf(a2[i]);
        }
    } else if (b == 21633) {
        if (t < NCLS) {
            ao1B[t] = f2bf(ao1[t]);
            ao2B[t] = f2bf(ao2[t]);
        }
    } else {                               // zero f1/f2: 64 blocks x 1024 floats
        long i = ((long)(b - 21634) * 256 + t) * 4;
        *(float4*)&f1z[i] = (float4){0.f, 0.f, 0.f, 0.f};
    }
}

// ---------------------------------------------------------------- gemm1 + fused f-scores (r15 verbatim)
__global__ __launch_bounds__(256) void gemm1_fs(
    const unsigned short* __restrict__ A, const unsigned short* __restrict__ Bt,
    unsigned short* __restrict__ Cc, const unsigned short* __restrict__ a1B,
    const unsigned short* __restrict__ a2B, float* __restrict__ f1,
    float* __restrict__ f2)
{
    __shared__ unsigned short Alds[64][72];
    __shared__ unsigned short Blds[128][72];
    __shared__ float s1l[128], s2l[128];
    int t = threadIdx.x;
    int w = t >> 6, l = t & 63;
    int h = blockIdx.z;
    long aoff = (long)h * DH * NF + (long)blockIdx.y * 64 * NF;
    long boff = (long)blockIdx.x * 128 * NF;
    if (t < 128) { s1l[t] = 0.f; s2l[t] = 0.f; }
    f32x4 acc[8];
#pragma unroll
    for (int i = 0; i < 8; ++i) acc[i] = (f32x4){0.f, 0.f, 0.f, 0.f};

    for (int k0 = 0; k0 < NF; k0 += 64) {
#pragma unroll
        for (int it = 0; it < 2; ++it) {
            int ci = it * 256 + t;
            int r = ci >> 3, c8 = (ci & 7) * 8;
            *(short8*)&Alds[r][c8] = *(const short8*)&A[aoff + (long)r * NF + k0 + c8];
        }
#pragma unroll
        for (int it = 0; it < 4; ++it) {
            int ci = it * 256 + t;
            int r = ci >> 3, c8 = (ci & 7) * 8;
            *(short8*)&Blds[r][c8] = *(const short8*)&Bt[boff + (long)r * NF + k0 + c8];
        }
        __syncthreads();
        int arow = w * 16 + (l & 15);
        int koff = (l >> 4) * 8;
#pragma unroll
        for (int kc = 0; kc < 2; ++kc) {
            short8 af = *(const short8*)&Alds[arow][kc * 32 + koff];
#pragma unroll
            for (int dt = 0; dt < 8; ++dt) {
                short8 bf = *(const short8*)&Blds[dt * 16 + (l & 15)][kc * 32 + koff];
                acc[dt] = __builtin_amdgcn_mfma_f32_16x16x32_bf16(af, bf, acc[dt], 0, 0, 0);
            }
        }
        __syncthreads();
    }
    long coff = (long)h * DH * NN + ((long)blockIdx.y * 64) * NN + blockIdx.x * 128;
    int mrow = w * 16 + (l >> 4) * 4;
    int dbase = blockIdx.y * 64;
#pragma unroll
    for (int dt = 0; dt < 8; ++dt) {
        int n = dt * 16 + (l & 15);
        float p1 = 0.f, p2 = 0.f;
#pragma unroll
        for (int r = 0; r < 4; ++r) {
            unsigned short bw = f2bf(acc[dt][r]);
            Cc[coff + (long)(mrow + r) * NN + n] = bw;
            float vf = bf2f(bw);
            int d = dbase + mrow + r;
            p1 += vf * bf2f(a1B[h * DH + d]);
            p2 += vf * bf2f(a2B[h * DH + d]);
        }
        atomicAdd(&s1l[n], p1);
        atomicAdd(&s2l[n], p2);
    }
    __syncthreads();
    if (t < 128) {
        int n = blockIdx.x * 128 + t;
        atomicAdd(&f1[h * NN + n], s1l[t] * LOG2E);
        atomicAdd(&f2[h * NN + n], s2l[t] * LOG2E);
    }
}

// ---------------------------------------------------------------- gemm2 + fused combinew (r15 verbatim)
__global__ __launch_bounds__(256) void gemm2c(
    const unsigned short* __restrict__ A, const unsigned short* __restrict__ Bt,
    const unsigned short* __restrict__ ao1B, const unsigned short* __restrict__ ao2B,
    unsigned short* __restrict__ WhoT, float* __restrict__ g1, float* __restrict__ g2)
{
    __shared__ unsigned short Alds[64][72];
    __shared__ unsigned short Blds[64][72];
    __shared__ float s1l[64], s2l[64];
    int t = threadIdx.x;
    int w = t >> 6, l = t & 63;
    int n0 = blockIdx.x * 64;
    if (t < 64) { s1l[t] = 0.f; s2l[t] = 0.f; }
    f32x4 acc[4];
#pragma unroll
    for (int i = 0; i < 4; ++i) acc[i] = (f32x4){0.f, 0.f, 0.f, 0.f};

    for (int k0 = 0; k0 < NF; k0 += 64) {
#pragma unroll
        for (int it = 0; it < 2; ++it) {
            int ci = it * 256 + t;
            int r = ci >> 3, c8 = (ci & 7) * 8;
            *(short8*)&Alds[r][c8] = *(const short8*)&A[(long)r * NF + k0 + c8];
        }
#pragma unroll
        for (int it = 0; it < 2; ++it) {
            int ci = it * 256 + t;
            int r = ci >> 3, c8 = (ci & 7) * 8;
            *(short8*)&Blds[r][c8] = *(const short8*)&Bt[(long)(n0 + r) * NF + k0 + c8];
        }
        __syncthreads();
        int arow = w * 16 + (l & 15);
        int koff = (l >> 4) * 8;
#pragma unroll
        for (int kc = 0; kc < 2; ++kc) {
            short8 af = *(const short8*)&Alds[arow][kc * 32 + koff];
#pragma unroll
            for (int dt = 0; dt < 4; ++dt) {
                short8 bf = *(const short8*)&Blds[dt * 16 + (l & 15)][kc * 32 + koff];
                acc[dt] = __builtin_amdgcn_mfma_f32_16x16x32_bf16(af, bf, acc[dt], 0, 0, 0);
            }
        }
        __syncthreads();
    }
    int mrow = w * 16 + (l >> 4) * 4;
#pragma unroll
    for (int dt = 0; dt < 4; ++dt) {
        int nl = dt * 16 + (l & 15);
        float p1 = 0.f, p2 = 0.f;
#pragma unroll
        for (int r = 0; r < 4; ++r) {
            int c = mrow + r;
            unsigned short bw = f2bf(acc[dt][r]);
            WhoT[(long)c * NN + n0 + nl] = bw;
            float vf = bf2f(bw);
            p1 += vf * bf2f(ao1B[c]);
            p2 += vf * bf2f(ao2B[c]);
        }
        atomicAdd(&s1l[nl], p1);
        atomicAdd(&s2l[nl], p2);
    }
    __syncthreads();
    if (t < 64) {
        g1[n0 + t] = s1l[t] * LOG2E;
        g2[n0 + t] = s2l[t] * LOG2E;
    }
}

// ------------------------------------------ legacy P-tile builder (fallback; exp2 domain)
static __device__ __forceinline__ float build_p16(
    unsigned int bits, float fi, const float* f2s, int pc0,
    short8& p0, short8& p1)
{
    float lsum = 0.f;
#pragma unroll
    for (int cc = 0; cc < 16; ++cc) {
        float wgt = 0.f;
        if ((bits >> cc) & 1u) {
            float e = fi + f2s[pc0 + cc];
            e = e > 0.f ? e : ALPHA * e;
            e = fminf(e, 60.f);
            wgt = fast_exp2(e);
        }
        unsigned short bw = f2bf(wgt);
        lsum += bf2f(bw);
        if (cc < 8) p0[cc] = (short)bw;
        else        p1[cc - 8] = (short)bw;
    }
    return lsum;
}

// ------------------------------------------ register A-fragment builder v3
static __device__ __forceinline__ void build_pfrag3(
    unsigned long long wpair, float fi, const float* __restrict__ f2g,
    int kgrp, short8& a0, short8& a1)
{
    int4v av0, av1;
#pragma unroll
    for (int kc = 0; kc < 2; ++kc) {
        unsigned bits = (unsigned)(wpair >> (kc * 32 + kgrp * 8)) & 0xFFu;
        const float4* fp = (const float4*)(f2g + kc * 32 + kgrp * 8);
        float4 fv0 = fp[0], fv1 = fp[1];
        float ev[8] = {fv0.x, fv0.y, fv0.z, fv0.w, fv1.x, fv1.y, fv1.z, fv1.w};
#pragma unroll
        for (int jj = 0; jj < 8; jj += 2) {
            float e0 = fi + ev[jj], e1 = fi + ev[jj + 1];
            e0 = fmaxf(e0, ALPHA * e0);
            e1 = fmaxf(e1, ALPHA * e1);
            float w0 = fast_exp2(e0), w1 = fast_exp2(e1);
            w0 = ((bits >> jj) & 1u) ? w0 : 0.f;
            w1 = ((bits >> (jj + 1)) & 1u) ? w1 : 0.f;
            float2 fv; fv.x = w0; fv.y = w1;
            __hip_bfloat162 pk = __float22bfloat162_rn(fv);
            unsigned pu; __builtin_memcpy(&pu, &pk, 4);
            if (kc == 0) av0[jj >> 1] = (int)pu;
            else         av1[jj >> 1] = (int)pu;
        }
    }
    a0 = __builtin_bit_cast(short8, av0);
    a1 = __builtin_bit_cast(short8, av1);
}

// ---------------------------------------------------------------- attn1 direct (ws fallback)
__global__ __launch_bounds__(256) void attn1_direct(
    const float* __restrict__ f1, const float* __restrict__ f2,
    const unsigned int* __restrict__ bm, const unsigned short* __restrict__ WhT,
    unsigned short* __restrict__ hcat)
{
    __shared__ unsigned short Plds[64][72];
    __shared__ unsigned short Wlds[128][72];
    __shared__ float f1s[64], f2s[64], ssum[64][4], srow[64];
    int t = threadIdx.x;
    int h = blockIdx.y;
    int i0 = blockIdx.x * 64;
    int w = t >> 6, l = t & 63;
    if (t < 64) f1s[t] = f1[h * NN + i0 + t];
    f32x4 acc[8];
#pragma unroll
    for (int i = 0; i < 8; ++i) acc[i] = (f32x4){0.f, 0.f, 0.f, 0.f};
    float psum = 0.f;
    int pr = t >> 2, pc0 = (t & 3) * 16;
    const unsigned short* Wh_h = WhT + (long)h * DH * NN;

    for (int j0 = 0; j0 < NN; j0 += 64) {
        if (t < 64) f2s[t] = f2[h * NN + j0 + t];
        __syncthreads();
        {
            unsigned int word = bm[(long)(i0 + pr) * (NN / 32) + (j0 >> 5) + ((pc0 >> 5) & 1)];
            unsigned int bits = (word >> (pc0 & 16)) & 0xFFFFu;
            short8 p0, p1;
            psum += build_p16(bits, f1s[pr], f2s, pc0, p0, p1);
            *(short8*)&Plds[pr][pc0]     = p0;
            *(short8*)&Plds[pr][pc0 + 8] = p1;
        }
#pragma unroll
        for (int it = 0; it < 4; ++it) {
            int ci = it * 256 + t;
            int d = ci >> 3, c8 = (ci & 7) * 8;
            *(short8*)&Wlds[d][c8] = *(const short8*)&Wh_h[(long)d * NN + j0 + c8];
        }
        __syncthreads();
        int arow = w * 16 + (l & 15);
        int koff = (l >> 4) * 8;
#pragma unroll
        for (int kc = 0; kc < 2; ++kc) {
            short8 af = *(const short8*)&Plds[arow][kc * 32 + koff];
#pragma unroll
            for (int dt = 0; dt < 8; ++dt) {
                short8 bf = *(const short8*)&Wlds[dt * 16 + (l & 15)][kc * 32 + koff];
                acc[dt] = __builtin_amdgcn_mfma_f32_16x16x32_bf16(af, bf, acc[dt], 0, 0, 0);
            }
        }
        __syncthreads();
    }
    ssum[pr][t & 3] = psum;
    __syncthreads();
    if (t < 64) srow[t] = ssum[t][0] + ssum[t][1] + ssum[t][2] + ssum[t][3];
    __syncthreads();
    int mrow = w * 16 + (l >> 4) * 4;
#pragma unroll
    for (int dt = 0; dt < 8; ++dt) {
        int d = dt * 16 + (l & 15);
#pragma unroll
        for (int r = 0; r < 4; ++r) {
            float v = acc[dt][r] / fmaxf(srow[mrow + r], 1e-20f);
            v = v > 0.f ? v : __expf(v) - 1.f;
            hcat[(long)(i0 + mrow + r) * (NHEADS * DH) + h * DH + d] = f2bf(v);
        }
    }
}

// ---------------------------------------------------------------- attn1 j-split, BK=128 (2 j-tiles per barrier)
__global__ __launch_bounds__(256) void attn1_part(
    const float* __restrict__ f1, const float* __restrict__ f2,
    const unsigned int* __restrict__ bm, const unsigned short* __restrict__ WhT,
    unsigned short* __restrict__ accp1, float* __restrict__ dsum1, int jspan)
{
    __shared__ unsigned short Wlds[128][136];      // [d][128 j + 8 pad]
    int t = threadIdx.x;
    int h = blockIdx.y;
    int i0 = blockIdx.x * 64;
    int jz = blockIdx.z;
    int w = t >> 6, l = t & 63;
    int m = l & 15, kgrp = l >> 4;
    int myrow = i0 + w * 16 + m;
    float fi = f1[h * NN + myrow];
    const unsigned int* bmrow = bm + (long)myrow * (NN / 32);
    const float* f2h = f2 + (long)h * NN;
    const unsigned short* Wh_h = WhT + (long)h * DH * NN;
    short8 ones;
#pragma unroll
    for (int i = 0; i < 8; ++i) ones[i] = (short)0x3F80;   // bf16 1.0
    f32x4 acc[8];
#pragma unroll
    for (int i = 0; i < 8; ++i) acc[i] = (f32x4){0.f, 0.f, 0.f, 0.f};
    f32x4 accd = (f32x4){0.f, 0.f, 0.f, 0.f};

    for (int j0 = jz * jspan; j0 < (jz + 1) * jspan; j0 += 128) {
        unsigned long long wp0, wp1;               // 128 mask bits (16B-aligned)
        __builtin_memcpy(&wp0, &bmrow[j0 >> 5], 8);
        __builtin_memcpy(&wp1, &bmrow[(j0 >> 5) + 2], 8);
#pragma unroll
        for (int it = 0; it < 8; ++it) {           // stage Wh tile [128 d][128 j]
            int ci = it * 256 + t;
            int d = ci >> 4, c8 = (ci & 15) * 8;
            *(short8*)&Wlds[d][c8] = *(const short8*)&Wh_h[(long)d * NN + j0 + c8];
        }
        short8 a0, a1, a2, a3;
        build_pfrag3(wp0, fi, f2h + j0, kgrp, a0, a1);
        build_pfrag3(wp1, fi, f2h + j0 + 64, kgrp, a2, a3);
        __syncthreads();
        accd = __builtin_amdgcn_mfma_f32_16x16x32_bf16(a0, ones, accd, 0, 0, 0);
        accd = __builtin_amdgcn_mfma_f32_16x16x32_bf16(a1, ones, accd, 0, 0, 0);
        accd = __builtin_amdgcn_mfma_f32_16x16x32_bf16(a2, ones, accd, 0, 0, 0);
        accd = __builtin_amdgcn_mfma_f32_16x16x32_bf16(a3, ones, accd, 0, 0, 0);
#pragma unroll
        for (int dt = 0; dt < 8; ++dt) {
            short8 b0 = *(const short8*)&Wlds[dt * 16 + m][kgrp * 8];
            acc[dt] = __builtin_amdgcn_mfma_f32_16x16x32_bf16(a0, b0, acc[dt], 0, 0, 0);
        }
#pragma unroll
        for (int dt = 0; dt < 8; ++dt) {
            short8 b1 = *(const short8*)&Wlds[dt * 16 + m][32 + kgrp * 8];
            acc[dt] = __builtin_amdgcn_mfma_f32_16x16x32_bf16(a1, b1, acc[dt], 0, 0, 0);
        }
#pragma unroll
        for (int dt = 0; dt < 8; ++dt) {
            short8 b2 = *(const short8*)&Wlds[dt * 16 + m][64 + kgrp * 8];
            acc[dt] = __builtin_amdgcn_mfma_f32_16x16x32_bf16(a2, b2, acc[dt], 0, 0, 0);
        }
#pragma unroll
        for (int dt = 0; dt < 8; ++dt) {
            short8 b3 = *(const short8*)&Wlds[dt * 16 + m][96 + kgrp * 8];
            acc[dt] = __builtin_amdgcn_mfma_f32_16x16x32_bf16(a3, b3, acc[dt], 0, 0, 0);
        }
        __syncthreads();
    }
    if (m == 0) {
#pragma unroll
        for (int r = 0; r < 4; ++r)
            dsum1[((long)jz * NHEADS + h) * NN + i0 + w * 16 + kgrp * 4 + r] = accd[r];
    }
    int mrow = w * 16 + kgrp * 4;
#pragma unroll
    for (int dt = 0; dt < 8; ++dt) {
        int d = dt * 16 + m;
#pragma unroll
        for (int r = 0; r < 4; ++r)
            accp1[((long)jz * NN + i0 + mrow + r) * (NHEADS * DH) + h * DH + d] = f2bf(acc[dt][r]);
    }
}

// combine attn1 partials -> hcat (bf16x4 per thread, r15 verbatim)
__global__ __launch_bounds__(256) void combine1(
    const unsigned short* __restrict__ accp1, const float* __restrict__ dsum1,
    unsigned short* __restrict__ hcat, int js)
{
    long idx4 = (long)blockIdx.x * 256 + threadIdx.x;
    int i = (int)(idx4 >> 8), c4 = (int)(idx4 & 255) * 4, h = c4 >> 7;
    float4 v = {0.f, 0.f, 0.f, 0.f};
    float s = 0.f;
    for (int jz = 0; jz < js; ++jz) {
        uint2 pv = *(const uint2*)&accp1[((long)jz * NN + i) * (NHEADS * DH) + c4];
        v.x += bf2f((unsigned short)(pv.x & 0xFFFFu));
        v.y += bf2f((unsigned short)(pv.x >> 16));
        v.z += bf2f((unsigned short)(pv.y & 0xFFFFu));
        v.w += bf2f((unsigned short)(pv.y >> 16));
        s += dsum1[((long)jz * NHEADS + h) * NN + i];
    }
    float inv = 1.f / fmaxf(s, 1e-20f);
    float o[4] = {v.x * inv, v.y * inv, v.z * inv, v.w * inv};
#pragma unroll
    for (int k = 0; k < 4; ++k) o[k] = o[k] > 0.f ? o[k] : __expf(o[k]) - 1.f;
    unsigned u0 = (unsigned)f2bf(o[0]) | ((unsigned)f2bf(o[1]) << 16);
    unsigned u1 = (unsigned)f2bf(o[2]) | ((unsigned)f2bf(o[3]) << 16);
    uint2 u; u.x = u0; u.y = u1;
    *(uint2*)&hcat[(long)i * (NHEADS * DH) + c4] = u;
}

// ---------------------------------------------------------------- attn2 (r15 verbatim)
__global__ __launch_bounds__(256) void attn2(
    const float* __restrict__ g1, const float* __restrict__ g2,
    const unsigned int* __restrict__ bm, const unsigned short* __restrict__ WhoT,
    unsigned short* __restrict__ accp, float* __restrict__ sp, int jspan)
{
    __shared__ unsigned short Wlds[64][72];
    int t = threadIdx.x;
    int i0 = blockIdx.x * 64;
    int jc = blockIdx.y;
    int w = t >> 6, l = t & 63;
    int m = l & 15, kgrp = l >> 4;
    int myrow = i0 + w * 16 + m;
    float fi = g1[myrow];
    const unsigned int* bmrow = bm + (long)myrow * (NN / 32);
    short8 ones;
#pragma unroll
    for (int i = 0; i < 8; ++i) ones[i] = (short)0x3F80;
    f32x4 acc[4];
#pragma unroll
    for (int i = 0; i < 4; ++i) acc[i] = (f32x4){0.f, 0.f, 0.f, 0.f};
    f32x4 accd = (f32x4){0.f, 0.f, 0.f, 0.f};

    for (int j0 = jc * jspan; j0 < (jc + 1) * jspan; j0 += 64) {
        unsigned long long wpair;
        __builtin_memcpy(&wpair, &bmrow[j0 >> 5], 8);
#pragma unroll
        for (int it = 0; it < 2; ++it) {
            int ci = it * 256 + t;
            int d = ci >> 3, c8 = (ci & 7) * 8;
            *(short8*)&Wlds[d][c8] = *(const short8*)&WhoT[(long)d * NN + j0 + c8];
        }
        short8 a0, a1;
        build_pfrag3(wpair, fi, g2 + j0, kgrp, a0, a1);
        __syncthreads();
        accd = __builtin_amdgcn_mfma_f32_16x16x32_bf16(a0, ones, accd, 0, 0, 0);
        accd = __builtin_amdgcn_mfma_f32_16x16x32_bf16(a1, ones, accd, 0, 0, 0);
#pragma unroll
        for (int dt = 0; dt < 4; ++dt) {
            short8 b0 = *(const short8*)&Wlds[dt * 16 + m][kgrp * 8];
            acc[dt] = __builtin_amdgcn_mfma_f32_16x16x32_bf16(a0, b0, acc[dt], 0, 0, 0);
        }
#pragma unroll
        for (int dt = 0; dt < 4; ++dt) {
            short8 b1 = *(const short8*)&Wlds[dt * 16 + m][32 + kgrp * 8];
            acc[dt] = __builtin_amdgcn_mfma_f32_16x16x32_bf16(a1, b1, acc[dt], 0, 0, 0);
        }
        __syncthreads();
    }
    if (m == 0) {
#pragma unroll
        for (int r = 0; r < 4; ++r)
            sp[(long)jc * NN + i0 + w * 16 + kgrp * 4 + r] = accd[r];
    }
    int mrow = w * 16 + kgrp * 4;
#pragma unroll
    for (int dt = 0; dt < 4; ++dt) {
        int d = dt * 16 + m;
#pragma unroll
        for (int r = 0; r < 4; ++r)
            accp[((long)jc * NN + i0 + mrow + r) * NCLS + d] = f2bf(acc[dt][r]);
    }
}

// ---------------------------------------------------------------- finalize (r15 verbatim)
__global__ __launch_bounds__(256) void finalize(
    const unsigned short* __restrict__ accp, const float* __restrict__ sp,
    float* __restrict__ out, int js)
{
    int t = threadIdx.x;
    int wv = t >> 6, l = t & 63;
    int r = blockIdx.x * 4 + wv;
    float v = 0.f, s = 0.f;
    for (int jc = 0; jc < js; ++jc) {
        v += bf2f(accp[((long)jc * NN + r) * NCLS + l]);
        s += sp[(long)jc * NN + r];
    }
    v /= fmaxf(s, 1e-20f);
    v = v > 0.f ? v : __expf(v) - 1.f;
    float m = v;
#pragma unroll
    for (int off = 32; off; off >>= 1) m = fmaxf(m, __shfl_xor(m, off));
    float ex = __expf(v - m);
#pragma unroll
    for (int off = 32; off; off >>= 1) ex += __shfl_xor(ex, off);
    out[(long)r * NCLS + l] = v - (m + __logf(ex));
}

// ---------------------------------------------------------------- launch
extern "C" void kernel_launch(void* const* d_in, const int* in_sizes, int n_in,
                              void* d_out, int out_size, void* d_ws, size_t ws_size,
                              hipStream_t stream)
{
    const float* x   = (const float*)d_in[0];
    const int*   adj = (const int*)d_in[1];
    const float* W   = (const float*)d_in[2];
    const float* a1  = (const float*)d_in[3];
    const float* a2  = (const float*)d_in[4];
    const float* Wo  = (const float*)d_in[5];
    const float* ao1 = (const float*)d_in[6];
    const float* ao2 = (const float*)d_in[7];
    float* out = (float*)d_out;

    const long SZ_XB   = (long)NN * NF * 2;
    const long SZ_AB   = (long)NHEADS * DH * 2;
    const long SZ_AOB  = (long)NCLS * 2;
    const long SZ_WT   = (long)NHEADS * DH * NF * 2;
    const long SZ_WOT  = (long)NCLS * NF * 2;
    const long SZ_WHT  = (long)NHEADS * DH * NN * 2;
    const long SZ_HCAT = (long)NN * NHEADS * DH * 2;
    const long SZ_WHOT = (long)NCLS * NN * 2;
    const long SZ_F    = (long)NHEADS * NN * 4;
    const long SZ_G    = (long)NN * 4;
    const long SZ_BM   = (long)NN * (NN / 32) * 4;
    const long SZ_AP1  = (long)NN * NHEADS * DH * 2;   // bf16 partials
    const long SZ_DS1  = (long)NHEADS * NN * 4;
    const long SZ_AP2  = (long)NN * NCLS * 2;          // bf16 partials
    const long SZ_SP2  = (long)NN * 4;
    long base = SZ_XB + 2 * SZ_AB + 2 * SZ_AOB + SZ_WT + SZ_WOT + SZ_WHT
              + SZ_HCAT + SZ_WHOT + 2 * SZ_F + 2 * SZ_G + SZ_BM
              + 40 * 256;

    int js1, js2;
    if ((size_t)(base + 4 * (SZ_AP1 + SZ_DS1) + 16 * (SZ_AP2 + SZ_SP2)) <= ws_size) {
        js1 = 4; js2 = 16;
    } else if ((size_t)(base + 4 * (SZ_AP1 + SZ_DS1) + 8 * (SZ_AP2 + SZ_SP2)) <= ws_size) {
        js1 = 4; js2 = 8;
    } else if ((size_t)(base + 2 * (SZ_AP1 + SZ_DS1) + 8 * (SZ_AP2 + SZ_SP2)) <= ws_size) {
        js1 = 2; js2 = 8;
    } else if ((size_t)(base + 16 * (SZ_AP2 + SZ_SP2)) <= ws_size) {
        js1 = 1; js2 = 16;
    } else if ((size_t)(base + 4 * (SZ_AP2 + SZ_SP2)) <= ws_size) {
        js1 = 1; js2 = 4;
    } else {
        diag_fill<<<dim3((out_size + 255) / 256), 256, 0, stream>>>(
            out, out_size, (float)(ws_size >> 20));
        return;
    }

    char* p = (char*)d_ws;
    auto alloc = [&](long bytes) { char* q = p; p += (bytes + 255) & ~255L; return q; };
    unsigned short* xB   = (unsigned short*)alloc(SZ_XB);
    unsigned short* a1B  = (unsigned short*)alloc(SZ_AB);
    unsigned short* a2B  = (unsigned short*)alloc(SZ_AB);
    unsigned short* ao1B = (unsigned short*)alloc(SZ_AOB);
    unsigned short* ao2B = (unsigned short*)alloc(SZ_AOB);
    unsigned short* WT   = (unsigned short*)alloc(SZ_WT);
    unsigned short* WoT  = (unsigned short*)alloc(SZ_WOT);
    unsigned short* WhT  = (unsigned short*)alloc(SZ_WHT);
    unsigned short* hcat = (unsigned short*)alloc(SZ_HCAT);
    unsigned short* WhoT = (unsigned short*)alloc(SZ_WHOT);
    float* f1 = (float*)alloc(SZ_F);
    float* f2 = (float*)alloc(SZ_F);
    float* g1 = (float*)alloc(SZ_G);
    float* g2 = (float*)alloc(SZ_G);
    unsigned int* bm = (unsigned int*)alloc(SZ_BM);
    unsigned short* accp2 = (unsigned short*)alloc(js2 * SZ_AP2);
    float* sp2   = (float*)alloc(js2 * SZ_SP2);
    unsigned short* accp1 = (unsigned short*)(js1 > 1 ? alloc(js1 * SZ_AP1) : nullptr);
    float* dsum1 = (float*)(js1 > 1 ? alloc(js1 * SZ_DS1) : nullptr);

    // 1. fused prep: bitmask + converts + transposes + f1/f2 zeroing
    prep<<<dim3(21698), 256, 0, stream>>>(
        x, adj, W, Wo, a1, a2, ao1, ao2,
        xB, bm, WT, WoT, a1B, a2B, ao1B, ao2B, f1);
    // 2. WhT = WT @ xB^T with fused f-scores (atomic)
    gemm1_fs<<<dim3(NN / 128, DH / 64, NHEADS), 256, 0, stream>>>(
        WT, xB, WhT, a1B, a2B, f1, f2);
    // 3. attention layer 1
    if (js1 > 1) {
        attn1_part<<<dim3(NN / 64, NHEADS, js1), 256, 0, stream>>>(
            f1, f2, bm, WhT, accp1, dsum1, NN / js1);
        combine1<<<dim3((int)(((long)NN * NHEADS * DH) / 1024)), 256, 0, stream>>>(
            accp1, dsum1, hcat, js1);
    } else {
        attn1_direct<<<dim3(NN / 64, NHEADS), 256, 0, stream>>>(f1, f2, bm, WhT, hcat);
    }
    // 4. WhoT = WoT @ hcat^T with fused g-scores
    gemm2c<<<dim3(NN / 64), 256, 0, stream>>>(WoT, hcat, ao1B, ao2B, WhoT, g1, g2);
    // 5. attention layer 2
    attn2<<<dim3(NN / 64, js2), 256, 0, stream>>>(g1, g2, bm, WhoT, accp2, sp2, NN / js2);
    // 6. finalize
    finalize<<<dim3(NN / 4), 256, 0, stream>>>(accp2, sp2, out, js2);
}

// Round 17
// 273.583 us; speedup vs baseline: 1.2326x; 1.0720x over previous
//
#include <hip/hip_runtime.h>
#include <hip/hip_bf16.h>

// GAT forward, MI355X. N=4096, NFEAT=1024, NHID=128, NHEADS=8, NCLASS=64.
// Inputs/outputs fp32 -> bf16 internally.
// Round 17: BK=128 (proven on attn1 in r16: barrier halving) applied to
// gemm1_fs (32->16 barriers; grid is dispatch-limited so LDS growth free)
// and attn2 (j-tiles 64->128). attn1/prep/gemm2c/combine1/finalize r16-verbatim.

#define NN    4096
#define NF    1024
#define DH    128
#define NHEADS 8
#define NCLS  64
#define ALPHA 0.2f
#define LOG2E 1.44269504f

using short8 = __attribute__((ext_vector_type(8))) short;
using f32x4  = __attribute__((ext_vector_type(4))) float;
using int4v  = __attribute__((ext_vector_type(4))) int;

static __device__ __forceinline__ float bf2f(unsigned short h) {
    return __uint_as_float(((unsigned int)h) << 16);
}
static __device__ __forceinline__ unsigned short f2bf(float f) {
    unsigned int u = __float_as_uint(f);
    u = (u + 0x7fffu + ((u >> 16) & 1u)) >> 16;
    return (unsigned short)u;
}
static __device__ __forceinline__ float fast_exp2(float x) {
    return __builtin_amdgcn_exp2f(x);
}

__global__ __launch_bounds__(256) void diag_fill(
    float* __restrict__ out, int n, float val)
{
    int i = blockIdx.x * 256 + threadIdx.x;
    if (i < n) out[i] = val;
}

// ---------------------------------------------------------------- prep (fused, r16 verbatim)
__global__ __launch_bounds__(256) void prep(
    const float* __restrict__ x, const int* __restrict__ adj,
    const float* __restrict__ W, const float* __restrict__ Wo,
    const float* __restrict__ a1, const float* __restrict__ a2,
    const float* __restrict__ ao1, const float* __restrict__ ao2,
    unsigned short* __restrict__ xB, unsigned int* __restrict__ bm,
    unsigned short* __restrict__ WT, unsigned short* __restrict__ WoT,
    unsigned short* __restrict__ a1B, unsigned short* __restrict__ a2B,
    unsigned short* __restrict__ ao1B, unsigned short* __restrict__ ao2B,
    float* __restrict__ f1z)
{
    __shared__ unsigned short tile[32][33];
    int b = blockIdx.x, t = threadIdx.x;
    if (b < 16384) {                       // bitmask (int4 + shfl-OR)
        long t4 = (long)b * 256 + t;
        int4v v = ((const int4v*)adj)[t4];
        unsigned nib = (v[0] > 0 ? 1u : 0u) | (v[1] > 0 ? 2u : 0u)
                     | (v[2] > 0 ? 4u : 0u) | (v[3] > 0 ? 8u : 0u);
        int l = t & 63;
        unsigned w = nib << (4 * (l & 7));
        w |= __shfl_xor(w, 1);
        w |= __shfl_xor(w, 2);
        w |= __shfl_xor(w, 4);
        if ((l & 7) == 0) bm[t4 >> 3] = w;
    } else if (b < 20480) {                // x fp32 -> bf16 (float4/thread)
        long i = ((long)(b - 16384) * 256 + t) * 4;
        float4 v = *(const float4*)&x[i];
        unsigned u0 = (unsigned)f2bf(v.x) | ((unsigned)f2bf(v.y) << 16);
        unsigned u1 = (unsigned)f2bf(v.z) | ((unsigned)f2bf(v.w) << 16);
        uint2 u; u.x = u0; u.y = u1;
        *(uint2*)&xB[i] = u;
    } else if (b < 21632) {                // transpose+convert W (z<8) / Wo (z=8)
        int tid = b - 20480;
        int z = tid >> 7;
        int rem = tid & 127;
        int bx = rem & 3, by = rem >> 2;
        const float* in; unsigned short* out; int C;
        if (z < 8) { in = W + (long)z * NF * DH; out = WT + (long)z * DH * NF; C = DH; }
        else       { in = Wo;                    out = WoT;                    C = NCLS; }
        int x0 = bx * 32, y0 = by * 32;
        if (x0 >= C) return;
        int tx = t & 31, ty = t >> 5;
        for (int yy = 0; yy < 32; yy += 8)
            tile[ty + yy][tx] = f2bf(in[(long)(y0 + ty + yy) * C + x0 + tx]);
        __syncthreads();
        for (int yy = 0; yy < 32; yy += 8)
            out[(long)(x0 + ty + yy) * NF + y0 + tx] = tile[tx][ty + yy];
    } else if (b == 21632) {
        for (int i = t; i < NHEADS * DH; i += 256) {
            a1B[i] = f2bf(a1[i]);
            a2B[i] = f2bf(a2[i]);
        }
    } else if (b == 21633) {
        if (t < NCLS) {
            ao1B[t] = f2bf(ao1[t]);
            ao2B[t] = f2bf(ao2[t]);
        }
    } else {                               // zero f1/f2: 64 blocks x 1024 floats
        long i = ((long)(b - 21634) * 256 + t) * 4;
        *(float4*)&f1z[i] = (float4){0.f, 0.f, 0.f, 0.f};
    }
}

// ---------------------------------------------------------------- gemm1 + fused f-scores, BK=128
__global__ __launch_bounds__(256) void gemm1_fs(
    const unsigned short* __restrict__ A, const unsigned short* __restrict__ Bt,
    unsigned short* __restrict__ Cc, const unsigned short* __restrict__ a1B,
    const unsigned short* __restrict__ a2B, float* __restrict__ f1,
    float* __restrict__ f2)
{
    __shared__ unsigned short Alds[64][136];
    __shared__ unsigned short Blds[128][136];
    __shared__ float s1l[128], s2l[128];
    int t = threadIdx.x;
    int w = t >> 6, l = t & 63;
    int h = blockIdx.z;
    long aoff = (long)h * DH * NF + (long)blockIdx.y * 64 * NF;
    long boff = (long)blockIdx.x * 128 * NF;
    if (t < 128) { s1l[t] = 0.f; s2l[t] = 0.f; }
    f32x4 acc[8];
#pragma unroll
    for (int i = 0; i < 8; ++i) acc[i] = (f32x4){0.f, 0.f, 0.f, 0.f};

    for (int k0 = 0; k0 < NF; k0 += 128) {
#pragma unroll
        for (int it = 0; it < 4; ++it) {          // A: 64 rows x 128 cols
            int ci = it * 256 + t;
            int r = ci >> 4, c8 = (ci & 15) * 8;
            *(short8*)&Alds[r][c8] = *(const short8*)&A[aoff + (long)r * NF + k0 + c8];
        }
#pragma unroll
        for (int it = 0; it < 8; ++it) {          // B: 128 rows x 128 cols
            int ci = it * 256 + t;
            int r = ci >> 4, c8 = (ci & 15) * 8;
            *(short8*)&Blds[r][c8] = *(const short8*)&Bt[boff + (long)r * NF + k0 + c8];
        }
        __syncthreads();
        int arow = w * 16 + (l & 15);
        int koff = (l >> 4) * 8;
#pragma unroll
        for (int kc = 0; kc < 4; ++kc) {
            short8 af = *(const short8*)&Alds[arow][kc * 32 + koff];
#pragma unroll
            for (int dt = 0; dt < 8; ++dt) {
                short8 bf = *(const short8*)&Blds[dt * 16 + (l & 15)][kc * 32 + koff];
                acc[dt] = __builtin_amdgcn_mfma_f32_16x16x32_bf16(af, bf, acc[dt], 0, 0, 0);
            }
        }
        __syncthreads();
    }
    long coff = (long)h * DH * NN + ((long)blockIdx.y * 64) * NN + blockIdx.x * 128;
    int mrow = w * 16 + (l >> 4) * 4;
    int dbase = blockIdx.y * 64;
#pragma unroll
    for (int dt = 0; dt < 8; ++dt) {
        int n = dt * 16 + (l & 15);
        float p1 = 0.f, p2 = 0.f;
#pragma unroll
        for (int r = 0; r < 4; ++r) {
            unsigned short bw = f2bf(acc[dt][r]);
            Cc[coff + (long)(mrow + r) * NN + n] = bw;
            float vf = bf2f(bw);
            int d = dbase + mrow + r;
            p1 += vf * bf2f(a1B[h * DH + d]);
            p2 += vf * bf2f(a2B[h * DH + d]);
        }
        atomicAdd(&s1l[n], p1);
        atomicAdd(&s2l[n], p2);
    }
    __syncthreads();
    if (t < 128) {
        int n = blockIdx.x * 128 + t;
        atomicAdd(&f1[h * NN + n], s1l[t] * LOG2E);
        atomicAdd(&f2[h * NN + n], s2l[t] * LOG2E);
    }
}

// ---------------------------------------------------------------- gemm2 + fused combinew (r16 verbatim)
__global__ __launch_bounds__(256) void gemm2c(
    const unsigned short* __restrict__ A, const unsigned short* __restrict__ Bt,
    const unsigned short* __restrict__ ao1B, const unsigned short* __restrict__ ao2B,
    unsigned short* __restrict__ WhoT, float* __restrict__ g1, float* __restrict__ g2)
{
    __shared__ unsigned short Alds[64][72];
    __shared__ unsigned short Blds[64][72];
    __shared__ float s1l[64], s2l[64];
    int t = threadIdx.x;
    int w = t >> 6, l = t & 63;
    int n0 = blockIdx.x * 64;
    if (t < 64) { s1l[t] = 0.f; s2l[t] = 0.f; }
    f32x4 acc[4];
#pragma unroll
    for (int i = 0; i < 4; ++i) acc[i] = (f32x4){0.f, 0.f, 0.f, 0.f};

    for (int k0 = 0; k0 < NF; k0 += 64) {
#pragma unroll
        for (int it = 0; it < 2; ++it) {
            int ci = it * 256 + t;
            int r = ci >> 3, c8 = (ci & 7) * 8;
            *(short8*)&Alds[r][c8] = *(const short8*)&A[(long)r * NF + k0 + c8];
        }
#pragma unroll
        for (int it = 0; it < 2; ++it) {
            int ci = it * 256 + t;
            int r = ci >> 3, c8 = (ci & 7) * 8;
            *(short8*)&Blds[r][c8] = *(const short8*)&Bt[(long)(n0 + r) * NF + k0 + c8];
        }
        __syncthreads();
        int arow = w * 16 + (l & 15);
        int koff = (l >> 4) * 8;
#pragma unroll
        for (int kc = 0; kc < 2; ++kc) {
            short8 af = *(const short8*)&Alds[arow][kc * 32 + koff];
#pragma unroll
            for (int dt = 0; dt < 4; ++dt) {
                short8 bf = *(const short8*)&Blds[dt * 16 + (l & 15)][kc * 32 + koff];
                acc[dt] = __builtin_amdgcn_mfma_f32_16x16x32_bf16(af, bf, acc[dt], 0, 0, 0);
            }
        }
        __syncthreads();
    }
    int mrow = w * 16 + (l >> 4) * 4;
#pragma unroll
    for (int dt = 0; dt < 4; ++dt) {
        int nl = dt * 16 + (l & 15);
        float p1 = 0.f, p2 = 0.f;
#pragma unroll
        for (int r = 0; r < 4; ++r) {
            int c = mrow + r;
            unsigned short bw = f2bf(acc[dt][r]);
            WhoT[(long)c * NN + n0 + nl] = bw;
            float vf = bf2f(bw);
            p1 += vf * bf2f(ao1B[c]);
            p2 += vf * bf2f(ao2B[c]);
        }
        atomicAdd(&s1l[nl], p1);
        atomicAdd(&s2l[nl], p2);
    }
    __syncthreads();
    if (t < 64) {
        g1[n0 + t] = s1l[t] * LOG2E;
        g2[n0 + t] = s2l[t] * LOG2E;
    }
}

// ------------------------------------------ legacy P-tile builder (fallback; exp2 domain)
static __device__ __forceinline__ float build_p16(
    unsigned int bits, float fi, const float* f2s, int pc0,
    short8& p0, short8& p1)
{
    float lsum = 0.f;
#pragma unroll
    for (int cc = 0; cc < 16; ++cc) {
        float wgt = 0.f;
        if ((bits >> cc) & 1u) {
            float e = fi + f2s[pc0 + cc];
            e = e > 0.f ? e : ALPHA * e;
            e = fminf(e, 60.f);
            wgt = fast_exp2(e);
        }
        unsigned short bw = f2bf(wgt);
        lsum += bf2f(bw);
        if (cc < 8) p0[cc] = (short)bw;
        else        p1[cc - 8] = (short)bw;
    }
    return lsum;
}

// ------------------------------------------ register A-fragment builder v3
static __device__ __forceinline__ void build_pfrag3(
    unsigned long long wpair, float fi, const float* __restrict__ f2g,
    int kgrp, short8& a0, short8& a1)
{
    int4v av0, av1;
#pragma unroll
    for (int kc = 0; kc < 2; ++kc) {
        unsigned bits = (unsigned)(wpair >> (kc * 32 + kgrp * 8)) & 0xFFu;
        const float4* fp = (const float4*)(f2g + kc * 32 + kgrp * 8);
        float4 fv0 = fp[0], fv1 = fp[1];
        float ev[8] = {fv0.x, fv0.y, fv0.z, fv0.w, fv1.x, fv1.y, fv1.z, fv1.w};
#pragma unroll
        for (int jj = 0; jj < 8; jj += 2) {
            float e0 = fi + ev[jj], e1 = fi + ev[jj + 1];
            e0 = fmaxf(e0, ALPHA * e0);
            e1 = fmaxf(e1, ALPHA * e1);
            float w0 = fast_exp2(e0), w1 = fast_exp2(e1);
            w0 = ((bits >> jj) & 1u) ? w0 : 0.f;
            w1 = ((bits >> (jj + 1)) & 1u) ? w1 : 0.f;
            float2 fv; fv.x = w0; fv.y = w1;
            __hip_bfloat162 pk = __float22bfloat162_rn(fv);
            unsigned pu; __builtin_memcpy(&pu, &pk, 4);
            if (kc == 0) av0[jj >> 1] = (int)pu;
            else         av1[jj >> 1] = (int)pu;
        }
    }
    a0 = __builtin_bit_cast(short8, av0);
    a1 = __builtin_bit_cast(short8, av1);
}

// ---------------------------------------------------------------- attn1 direct (ws fallback)
__global__ __launch_bounds__(256) void attn1_direct(
    const float* __restrict__ f1, const float* __restrict__ f2,
    const unsigned int* __restrict__ bm, const unsigned short* __restrict__ WhT,
    unsigned short* __restrict__ hcat)
{
    __shared__ unsigned short Plds[64][72];
    __shared__ unsigned short Wlds[128][72];
    __shared__ float f1s[64], f2s[64], ssum[64][4], srow[64];
    int t = threadIdx.x;
    int h = blockIdx.y;
    int i0 = blockIdx.x * 64;
    int w = t >> 6, l = t & 63;
    if (t < 64) f1s[t] = f1[h * NN + i0 + t];
    f32x4 acc[8];
#pragma unroll
    for (int i = 0; i < 8; ++i) acc[i] = (f32x4){0.f, 0.f, 0.f, 0.f};
    float psum = 0.f;
    int pr = t >> 2, pc0 = (t & 3) * 16;
    const unsigned short* Wh_h = WhT + (long)h * DH * NN;

    for (int j0 = 0; j0 < NN; j0 += 64) {
        if (t < 64) f2s[t] = f2[h * NN + j0 + t];
        __syncthreads();
        {
            unsigned int word = bm[(long)(i0 + pr) * (NN / 32) + (j0 >> 5) + ((pc0 >> 5) & 1)];
            unsigned int bits = (word >> (pc0 & 16)) & 0xFFFFu;
            short8 p0, p1;
            psum += build_p16(bits, f1s[pr], f2s, pc0, p0, p1);
            *(short8*)&Plds[pr][pc0]     = p0;
            *(short8*)&Plds[pr][pc0 + 8] = p1;
        }
#pragma unroll
        for (int it = 0; it < 4; ++it) {
            int ci = it * 256 + t;
            int d = ci >> 3, c8 = (ci & 7) * 8;
            *(short8*)&Wlds[d][c8] = *(const short8*)&Wh_h[(long)d * NN + j0 + c8];
        }
        __syncthreads();
        int arow = w * 16 + (l & 15);
        int koff = (l >> 4) * 8;
#pragma unroll
        for (int kc = 0; kc < 2; ++kc) {
            short8 af = *(const short8*)&Plds[arow][kc * 32 + koff];
#pragma unroll
            for (int dt = 0; dt < 8; ++dt) {
                short8 bf = *(const short8*)&Wlds[dt * 16 + (l & 15)][kc * 32 + koff];
                acc[dt] = __builtin_amdgcn_mfma_f32_16x16x32_bf16(af, bf, acc[dt], 0, 0, 0);
            }
        }
        __syncthreads();
    }
    ssum[pr][t & 3] = psum;
    __syncthreads();
    if (t < 64) srow[t] = ssum[t][0] + ssum[t][1] + ssum[t][2] + ssum[t][3];
    __syncthreads();
    int mrow = w * 16 + (l >> 4) * 4;
#pragma unroll
    for (int dt = 0; dt < 8; ++dt) {
        int d = dt * 16 + (l & 15);
#pragma unroll
        for (int r = 0; r < 4; ++r) {
            float v = acc[dt][r] / fmaxf(srow[mrow + r], 1e-20f);
            v = v > 0.f ? v : __expf(v) - 1.f;
            hcat[(long)(i0 + mrow + r) * (NHEADS * DH) + h * DH + d] = f2bf(v);
        }
    }
}

// ---------------------------------------------------------------- attn1 j-split, BK=128 (r16 verbatim)
__global__ __launch_bounds__(256) void attn1_part(
    const float* __restrict__ f1, const float* __restrict__ f2,
    const unsigned int* __restrict__ bm, const unsigned short* __restrict__ WhT,
    unsigned short* __restrict__ accp1, float* __restrict__ dsum1, int jspan)
{
    __shared__ unsigned short Wlds[128][136];      // [d][128 j + 8 pad]
    int t = threadIdx.x;
    int h = blockIdx.y;
    int i0 = blockIdx.x * 64;
    int jz = blockIdx.z;
    int w = t >> 6, l = t & 63;
    int m = l & 15, kgrp = l >> 4;
    int myrow = i0 + w * 16 + m;
    float fi = f1[h * NN + myrow];
    const unsigned int* bmrow = bm + (long)myrow * (NN / 32);
    const float* f2h = f2 + (long)h * NN;
    const unsigned short* Wh_h = WhT + (long)h * DH * NN;
    short8 ones;
#pragma unroll
    for (int i = 0; i < 8; ++i) ones[i] = (short)0x3F80;   // bf16 1.0
    f32x4 acc[8];
#pragma unroll
    for (int i = 0; i < 8; ++i) acc[i] = (f32x4){0.f, 0.f, 0.f, 0.f};
    f32x4 accd = (f32x4){0.f, 0.f, 0.f, 0.f};

    for (int j0 = jz * jspan; j0 < (jz + 1) * jspan; j0 += 128) {
        unsigned long long wp0, wp1;
        __builtin_memcpy(&wp0, &bmrow[j0 >> 5], 8);
        __builtin_memcpy(&wp1, &bmrow[(j0 >> 5) + 2], 8);
#pragma unroll
        for (int it = 0; it < 8; ++it) {           // stage Wh tile [128 d][128 j]
            int ci = it * 256 + t;
            int d = ci >> 4, c8 = (ci & 15) * 8;
            *(short8*)&Wlds[d][c8] = *(const short8*)&Wh_h[(long)d * NN + j0 + c8];
        }
        short8 a0, a1, a2, a3;
        build_pfrag3(wp0, fi, f2h + j0, kgrp, a0, a1);
        build_pfrag3(wp1, fi, f2h + j0 + 64, kgrp, a2, a3);
        __syncthreads();
        accd = __builtin_amdgcn_mfma_f32_16x16x32_bf16(a0, ones, accd, 0, 0, 0);
        accd = __builtin_amdgcn_mfma_f32_16x16x32_bf16(a1, ones, accd, 0, 0, 0);
        accd = __builtin_amdgcn_mfma_f32_16x16x32_bf16(a2, ones, accd, 0, 0, 0);
        accd = __builtin_amdgcn_mfma_f32_16x16x32_bf16(a3, ones, accd, 0, 0, 0);
#pragma unroll
        for (int dt = 0; dt < 8; ++dt) {
            short8 b0 = *(const short8*)&Wlds[dt * 16 + m][kgrp * 8];
            acc[dt] = __builtin_amdgcn_mfma_f32_16x16x32_bf16(a0, b0, acc[dt], 0, 0, 0);
        }
#pragma unroll
        for (int dt = 0; dt < 8; ++dt) {
            short8 b1 = *(const short8*)&Wlds[dt * 16 + m][32 + kgrp * 8];
            acc[dt] = __builtin_amdgcn_mfma_f32_16x16x32_bf16(a1, b1, acc[dt], 0, 0, 0);
        }
#pragma unroll
        for (int dt = 0; dt < 8; ++dt) {
            short8 b2 = *(const short8*)&Wlds[dt * 16 + m][64 + kgrp * 8];
            acc[dt] = __builtin_amdgcn_mfma_f32_16x16x32_bf16(a2, b2, acc[dt], 0, 0, 0);
        }
#pragma unroll
        for (int dt = 0; dt < 8; ++dt) {
            short8 b3 = *(const short8*)&Wlds[dt * 16 + m][96 + kgrp * 8];
            acc[dt] = __builtin_amdgcn_mfma_f32_16x16x32_bf16(a3, b3, acc[dt], 0, 0, 0);
        }
        __syncthreads();
    }
    if (m == 0) {
#pragma unroll
        for (int r = 0; r < 4; ++r)
            dsum1[((long)jz * NHEADS + h) * NN + i0 + w * 16 + kgrp * 4 + r] = accd[r];
    }
    int mrow = w * 16 + kgrp * 4;
#pragma unroll
    for (int dt = 0; dt < 8; ++dt) {
        int d = dt * 16 + m;
#pragma unroll
        for (int r = 0; r < 4; ++r)
            accp1[((long)jz * NN + i0 + mrow + r) * (NHEADS * DH) + h * DH + d] = f2bf(acc[dt][r]);
    }
}

// combine attn1 partials -> hcat (r16 verbatim)
__global__ __launch_bounds__(256) void combine1(
    const unsigned short* __restrict__ accp1, const float* __restrict__ dsum1,
    unsigned short* __restrict__ hcat, int js)
{
    long idx4 = (long)blockIdx.x * 256 + threadIdx.x;
    int i = (int)(idx4 >> 8), c4 = (int)(idx4 & 255) * 4, h = c4 >> 7;
    float4 v = {0.f, 0.f, 0.f, 0.f};
    float s = 0.f;
    for (int jz = 0; jz < js; ++jz) {
        uint2 pv = *(const uint2*)&accp1[((long)jz * NN + i) * (NHEADS * DH) + c4];
        v.x += bf2f((unsigned short)(pv.x & 0xFFFFu));
        v.y += bf2f((unsigned short)(pv.x >> 16));
        v.z += bf2f((unsigned short)(pv.y & 0xFFFFu));
        v.w += bf2f((unsigned short)(pv.y >> 16));
        s += dsum1[((long)jz * NHEADS + h) * NN + i];
    }
    float inv = 1.f / fmaxf(s, 1e-20f);
    float o[4] = {v.x * inv, v.y * inv, v.z * inv, v.w * inv};
#pragma unroll
    for (int k = 0; k < 4; ++k) o[k] = o[k] > 0.f ? o[k] : __expf(o[k]) - 1.f;
    unsigned u0 = (unsigned)f2bf(o[0]) | ((unsigned)f2bf(o[1]) << 16);
    unsigned u1 = (unsigned)f2bf(o[2]) | ((unsigned)f2bf(o[3]) << 16);
    uint2 u; u.x = u0; u.y = u1;
    *(uint2*)&hcat[(long)i * (NHEADS * DH) + c4] = u;
}

// ---------------------------------------------------------------- attn2, BK=128
__global__ __launch_bounds__(256) void attn2(
    const float* __restrict__ g1, const float* __restrict__ g2,
    const unsigned int* __restrict__ bm, const unsigned short* __restrict__ WhoT,
    unsigned short* __restrict__ accp, float* __restrict__ sp, int jspan)
{
    __shared__ unsigned short Wlds[64][136];       // [c][128 j + 8 pad]
    int t = threadIdx.x;
    int i0 = blockIdx.x * 64;
    int jc = blockIdx.y;
    int w = t >> 6, l = t & 63;
    int m = l & 15, kgrp = l >> 4;
    int myrow = i0 + w * 16 + m;
    float fi = g1[myrow];
    const unsigned int* bmrow = bm + (long)myrow * (NN / 32);
    short8 ones;
#pragma unroll
    for (int i = 0; i < 8; ++i) ones[i] = (short)0x3F80;
    f32x4 acc[4];
#pragma unroll
    for (int i = 0; i < 4; ++i) acc[i] = (f32x4){0.f, 0.f, 0.f, 0.f};
    f32x4 accd = (f32x4){0.f, 0.f, 0.f, 0.f};

    for (int j0 = jc * jspan; j0 < (jc + 1) * jspan; j0 += 128) {
        unsigned long long wp0, wp1;
        __builtin_memcpy(&wp0, &bmrow[j0 >> 5], 8);
        __builtin_memcpy(&wp1, &bmrow[(j0 >> 5) + 2], 8);
#pragma unroll
        for (int it = 0; it < 4; ++it) {           // stage Who tile [64 c][128 j]
            int ci = it * 256 + t;
            int d = ci >> 4, c8 = (ci & 15) * 8;
            *(short8*)&Wlds[d][c8] = *(const short8*)&WhoT[(long)d * NN + j0 + c8];
        }
        short8 a0, a1, a2, a3;
        build_pfrag3(wp0, fi, g2 + j0, kgrp, a0, a1);
        build_pfrag3(wp1, fi, g2 + j0 + 64, kgrp, a2, a3);
        __syncthreads();
        accd = __builtin_amdgcn_mfma_f32_16x16x32_bf16(a0, ones, accd, 0, 0, 0);
        accd = __builtin_amdgcn_mfma_f32_16x16x32_bf16(a1, ones, accd, 0, 0, 0);
        accd = __builtin_amdgcn_mfma_f32_16x16x32_bf16(a2, ones, accd, 0, 0, 0);
        accd = __builtin_amdgcn_mfma_f32_16x16x32_bf16(a3, ones, accd, 0, 0, 0);
#pragma unroll
        for (int dt = 0; dt < 4; ++dt) {
            short8 b0 = *(const short8*)&Wlds[dt * 16 + m][kgrp * 8];
            acc[dt] = __builtin_amdgcn_mfma_f32_16x16x32_bf16(a0, b0, acc[dt], 0, 0, 0);
        }
#pragma unroll
        for (int dt = 0; dt < 4; ++dt) {
            short8 b1 = *(const short8*)&Wlds[dt * 16 + m][32 + kgrp * 8];
            acc[dt] = __builtin_amdgcn_mfma_f32_16x16x32_bf16(a1, b1, acc[dt], 0, 0, 0);
        }
#pragma unroll
        for (int dt = 0; dt < 4; ++dt) {
            short8 b2 = *(const short8*)&Wlds[dt * 16 + m][64 + kgrp * 8];
            acc[dt] = __builtin_amdgcn_mfma_f32_16x16x32_bf16(a2, b2, acc[dt], 0, 0, 0);
        }
#pragma unroll
        for (int dt = 0; dt < 4; ++dt) {
            short8 b3 = *(const short8*)&Wlds[dt * 16 + m][96 + kgrp * 8];
            acc[dt] = __builtin_amdgcn_mfma_f32_16x16x32_bf16(a3, b3, acc[dt], 0, 0, 0);
        }
        __syncthreads();
    }
    if (m == 0) {
#pragma unroll
        for (int r = 0; r < 4; ++r)
            sp[(long)jc * NN + i0 + w * 16 + kgrp * 4 + r] = accd[r];
    }
    int mrow = w * 16 + kgrp * 4;
#pragma unroll
    for (int dt = 0; dt < 4; ++dt) {
        int d = dt * 16 + m;
#pragma unroll
        for (int r = 0; r < 4; ++r)
            accp[((long)jc * NN + i0 + mrow + r) * NCLS + d] = f2bf(acc[dt][r]);
    }
}

// ---------------------------------------------------------------- finalize (r16 verbatim)
__global__ __launch_bounds__(256) void finalize(
    const unsigned short* __restrict__ accp, const float* __restrict__ sp,
    float* __restrict__ out, int js)
{
    int t = threadIdx.x;
    int wv = t >> 6, l = t & 63;
    int r = blockIdx.x * 4 + wv;
    float v = 0.f, s = 0.f;
    for (int jc = 0; jc < js; ++jc) {
        v += bf2f(accp[((long)jc * NN + r) * NCLS + l]);
        s += sp[(long)jc * NN + r];
    }
    v /= fmaxf(s, 1e-20f);
    v = v > 0.f ? v : __expf(v) - 1.f;
    float m = v;
#pragma unroll
    for (int off = 32; off; off >>= 1) m = fmaxf(m, __shfl_xor(m, off));
    float ex = __expf(v - m);
#pragma unroll
    for (int off = 32; off; off >>= 1) ex += __shfl_xor(ex, off);
    out[(long)r * NCLS + l] = v - (m + __logf(ex));
}

// ---------------------------------------------------------------- launch
extern "C" void kernel_launch(void* const* d_in, const int* in_sizes, int n_in,
                              void* d_out, int out_size, void* d_ws, size_t ws_size,
                              hipStream_t stream)
{
    const float* x   = (const float*)d_in[0];
    const int*   adj = (const int*)d_in[1];
    const float* W   = (const float*)d_in[2];
    const float* a1  = (const float*)d_in[3];
    const float* a2  = (const float*)d_in[4];
    const float* Wo  = (const float*)d_in[5];
    const float* ao1 = (const float*)d_in[6];
    const float* ao2 = (const float*)d_in[7];
    float* out = (float*)d_out;

    const long SZ_XB   = (long)NN * NF * 2;
    const long SZ_AB   = (long)NHEADS * DH * 2;
    const long SZ_AOB  = (long)NCLS * 2;
    const long SZ_WT   = (long)NHEADS * DH * NF * 2;
    const long SZ_WOT  = (long)NCLS * NF * 2;
    const long SZ_WHT  = (long)NHEADS * DH * NN * 2;
    const long SZ_HCAT = (long)NN * NHEADS * DH * 2;
    const long SZ_WHOT = (long)NCLS * NN * 2;
    const long SZ_F    = (long)NHEADS * NN * 4;
    const long SZ_G    = (long)NN * 4;
    const long SZ_BM   = (long)NN * (NN / 32) * 4;
    const long SZ_AP1  = (long)NN * NHEADS * DH * 2;   // bf16 partials
    const long SZ_DS1  = (long)NHEADS * NN * 4;
    const long SZ_AP2  = (long)NN * NCLS * 2;          // bf16 partials
    const long SZ_SP2  = (long)NN * 4;
    long base = SZ_XB + 2 * SZ_AB + 2 * SZ_AOB + SZ_WT + SZ_WOT + SZ_WHT
              + SZ_HCAT + SZ_WHOT + 2 * SZ_F + 2 * SZ_G + SZ_BM
              + 40 * 256;

    int js1, js2;
    if ((size_t)(base + 4 * (SZ_AP1 + SZ_DS1) + 16 * (SZ_AP2 + SZ_SP2)) <= ws_size) {
        js1 = 4; js2 = 16;
    } else if ((size_t)(base + 4 * (SZ_AP1 + SZ_DS1) + 8 * (SZ_AP2 + SZ_SP2)) <= ws_size) {
        js1 = 4; js2 = 8;
    } else if ((size_t)(base + 2 * (SZ_AP1 + SZ_DS1) + 8 * (SZ_AP2 + SZ_SP2)) <= ws_size) {
        js1 = 2; js2 = 8;
    } else if ((size_t)(base + 16 * (SZ_AP2 + SZ_SP2)) <= ws_size) {
        js1 = 1; js2 = 16;
    } else if ((size_t)(base + 4 * (SZ_AP2 + SZ_SP2)) <= ws_size) {
        js1 = 1; js2 = 4;
    } else {
        diag_fill<<<dim3((out_size + 255) / 256), 256, 0, stream>>>(
            out, out_size, (float)(ws_size >> 20));
        return;
    }

    char* p = (char*)d_ws;
    auto alloc = [&](long bytes) { char* q = p; p += (bytes + 255) & ~255L; return q; };
    unsigned short* xB   = (unsigned short*)alloc(SZ_XB);
    unsigned short* a1B  = (unsigned short*)alloc(SZ_AB);
    unsigned short* a2B  = (unsigned short*)alloc(SZ_AB);
    unsigned short* ao1B = (unsigned short*)alloc(SZ_AOB);
    unsigned short* ao2B = (unsigned short*)alloc(SZ_AOB);
    unsigned short* WT   = (unsigned short*)alloc(SZ_WT);
    unsigned short* WoT  = (unsigned short*)alloc(SZ_WOT);
    unsigned short* WhT  = (unsigned short*)alloc(SZ_WHT);
    unsigned short* hcat = (unsigned short*)alloc(SZ_HCAT);
    unsigned short* WhoT = (unsigned short*)alloc(SZ_WHOT);
    float* f1 = (float*)alloc(SZ_F);
    float* f2 = (float*)alloc(SZ_F);
    float* g1 = (float*)alloc(SZ_G);
    float* g2 = (float*)alloc(SZ_G);
    unsigned int* bm = (unsigned int*)alloc(SZ_BM);
    unsigned short* accp2 = (unsigned short*)alloc(js2 * SZ_AP2);
    float* sp2   = (float*)alloc(js2 * SZ_SP2);
    unsigned short* accp1 = (unsigned short*)(js1 > 1 ? alloc(js1 * SZ_AP1) : nullptr);
    float* dsum1 = (float*)(js1 > 1 ? alloc(js1 * SZ_DS1) : nullptr);

    // 1. fused prep: bitmask + converts + transposes + f1/f2 zeroing
    prep<<<dim3(21698), 256, 0, stream>>>(
        x, adj, W, Wo, a1, a2, ao1, ao2,
        xB, bm, WT, WoT, a1B, a2B, ao1B, ao2B, f1);
    // 2. WhT = WT @ xB^T with fused f-scores (atomic)
    gemm1_fs<<<dim3(NN / 128, DH / 64, NHEADS), 256, 0, stream>>>(
        WT, xB, WhT, a1B, a2B, f1, f2);
    // 3. attention layer 1
    if (js1 > 1) {
        attn1_part<<<dim3(NN / 64, NHEADS, js1), 256, 0, stream>>>(
            f1, f2, bm, WhT, accp1, dsum1, NN / js1);
        combine1<<<dim3((int)(((long)NN * NHEADS * DH) / 1024)), 256, 0, stream>>>(
            accp1, dsum1, hcat, js1);
    } else {
        attn1_direct<<<dim3(NN / 64, NHEADS), 256, 0, stream>>>(f1, f2, bm, WhT, hcat);
    }
    // 4. WhoT = WoT @ hcat^T with fused g-scores
    gemm2c<<<dim3(NN / 64), 256, 0, stream>>>(WoT, hcat, ao1B, ao2B, WhoT, g1, g2);
    // 5. attention layer 2
    attn2<<<dim3(NN / 64, js2), 256, 0, stream>>>(g1, g2, bm, WhoT, accp2, sp2, NN / js2);
    // 6. finalize
    finalize<<<dim3(NN / 4), 256, 0, stream>>>(accp2, sp2, out, js2);
}